// Round 14
// baseline (2214.107 us; speedup 1.0000x reference)
//
#include <hip/hip_runtime.h>
#include <hip/hip_bf16.h>
#include <type_traits>
#include <math.h>

typedef unsigned short u16;
typedef __attribute__((ext_vector_type(8))) short  s16x8;
typedef __attribute__((ext_vector_type(4))) short  s16x4;
typedef __attribute__((ext_vector_type(8))) __bf16 b16x8;
typedef __attribute__((ext_vector_type(4))) float  f32x4;

#define S_LEN 4096
#define NB    4
#define EMB   1024
#define NH    16
#define HD    64
#define NROWS (NB * S_LEN)   // 16384
#define KDIM  1024
#define BHSTRIDE (S_LEN * HD)   // 262144 u16 per (b,h) for Kp / Vt
#define QSCALE 0.18033688f      // 0.125 * log2(e): scores land in log2-domain
#define THR2   11.5429f         // defer-max threshold, 8 nats in log2 units

static __device__ __forceinline__ u16 f2b(float f) {
  __hip_bfloat16 h = __float2bfloat16(f);
  return __builtin_bit_cast(u16, h);
}

static __device__ __forceinline__ float exp2_fast(float x) {
#if __has_builtin(__builtin_amdgcn_exp2f)
  return __builtin_amdgcn_exp2f(x);   // raw v_exp_f32
#else
  return exp2f(x);
#endif
}

// ---- MFMA shim ----
template <typename T, typename = void>
struct mfma_takes : std::false_type {};
template <typename T>
struct mfma_takes<T, std::void_t<decltype(__builtin_amdgcn_mfma_f32_16x16x32_bf16(
    std::declval<T>(), std::declval<T>(), std::declval<f32x4>(), 0, 0, 0))>> : std::true_type {};

template <typename AB>
static __device__ __forceinline__ f32x4 mfma_any(AB a, AB b, f32x4 c) {
  return __builtin_amdgcn_mfma_f32_16x16x32_bf16(a, b, c, 0, 0, 0);
}

template <typename S8 = s16x8, typename B8 = b16x8>
static __device__ __forceinline__ f32x4 MFMA_BF16(s16x8 a, s16x8 b, f32x4 c) {
  if constexpr (mfma_takes<S8>::value)
    return mfma_any<S8>(__builtin_bit_cast(S8, a), __builtin_bit_cast(S8, b), c);
  else
    return mfma_any<B8>(__builtin_bit_cast(B8, a), __builtin_bit_cast(B8, b), c);
}

static __device__ __forceinline__ void gld_lds16(const void* g, void* l) {
  __builtin_amdgcn_global_load_lds((const __attribute__((address_space(1))) void*)g,
                                   (__attribute__((address_space(3))) void*)l, 16, 0, 0);
}

// ---------------- fp32 -> bf16 conversion (x) ----------------
__global__ __launch_bounds__(256) void cvt_x_kernel(const float* __restrict__ in,
                                                    u16* __restrict__ out) {
  long i = ((long)blockIdx.x * 256 + threadIdx.x) * 8;
  float4 a = *(const float4*)(in + i);
  float4 b = *(const float4*)(in + i + 4);
  s16x8 o;
  o[0] = (short)f2b(a.x); o[1] = (short)f2b(a.y); o[2] = (short)f2b(a.z); o[3] = (short)f2b(a.w);
  o[4] = (short)f2b(b.x); o[5] = (short)f2b(b.y); o[6] = (short)f2b(b.z); o[7] = (short)f2b(b.w);
  *(s16x8*)(out + i) = o;
}

// ---------------- transpose + convert 4 x W, fused ----------------
__global__ __launch_bounds__(256) void transpose_cvt4_kernel(
    const float* __restrict__ W0, const float* __restrict__ W1,
    const float* __restrict__ W2, const float* __restrict__ W3,
    u16* __restrict__ D0, u16* __restrict__ D1, u16* __restrict__ D2, u16* __restrict__ D3) {
  __shared__ float tile[32][33];
  const float* W; u16* D;
  switch (blockIdx.z) {
    case 0:  W = W0; D = D0; break;
    case 1:  W = W1; D = D1; break;
    case 2:  W = W2; D = D2; break;
    default: W = W3; D = D3; break;
  }
  int n0 = blockIdx.x * 32, k0 = blockIdx.y * 32;
  int tx = threadIdx.x & 31, ty = threadIdx.x >> 5;
#pragma unroll
  for (int i = ty; i < 32; i += 8)
    tile[i][tx] = W[(long)(k0 + i) * EMB + n0 + tx];
  __syncthreads();
#pragma unroll
  for (int i = ty; i < 32; i += 8)
    D[(long)(n0 + i) * EMB + k0 + tx] = f2b(tile[tx][i]);
}

// ========== 256x256 GEMM, 16 waves, 64KB LDS (4 slots) -> 2 blocks/CU ==========
// Slots (u16 off): SA0=0, SA1=8192, SB0=16384, SB1=24576. Tile t reads:
//   P1: SA0(mh0)+SB0  P2: SA0(mh1)  P3: SA1(mh0)+SB1  P4: SA1(mh1)
// Stage windows (slot free = after bar2 of its last-read phase):
//   P1: A(t,+32)->SA1 (free since P4(t-1))   P2: B(t+1,+0)->SB0 (free after P1)
//   P3: A(t+1,+0)->SA0 (free after P2)       P4: B(t+1,+32)->SB1 (free after P3)
// Drains (1 stage/phase): vm(2)@P1, vm(1)@P2, vm(2)@P3, vm(2)@P4:
//   P4-end drains P2's SB0 (read P1(t+1))  P1-end drains P3's SA0 (read P2(t+1))
//   P2-end vm(1) drains P4's SB1 + P1's SA1 (both read P3(t))
// SA1 is the short-lead stage (P1->P3); hidden by the second resident block.
// Prologue: SA0,SB0,SB1 staged; vm(1); bar. P1(0) stages SA1.
#define SA0_ 0
#define SA1_ 8192
#define SB0_ 16384
#define SB1_ 24576

__global__ __launch_bounds__(1024, 8) void gemm8p_kernel(
    const u16* __restrict__ A, const u16* __restrict__ Bt,
    const float* __restrict__ b0, const float* __restrict__ b1, const float* __restrict__ b2,
    void* __restrict__ Cp, u16* __restrict__ Qb, u16* __restrict__ Kp, u16* __restrict__ Vt,
    int N, int out_f32) {
  __shared__ __align__(16) u16 smem[32768];   // 64 KiB
  const int tid = threadIdx.x;
  const int w = tid >> 6, lane = tid & 63;
  const int wm = w >> 2, wn = w & 3;          // 4x4 wave grid, 64x64 each
  const int frow = lane & 15, fg = lane >> 4;

  const int nwg = gridDim.x;
  const int bid = ((int)blockIdx.x & 7) * (nwg >> 3) + ((int)blockIdx.x >> 3);
  const int nbn = N >> 8;
  const int bm = bid / nbn, bn = bid % nbn;

  int offA[4];
#pragma unroll
  for (int j = 0; j < 4; j++) {
    int row = wm * 64 + j * 16 + frow;
    offA[j] = row * 32 + ((fg ^ ((row ^ (row >> 2)) & 3)) << 3);
  }
  int offB[4];
#pragma unroll
  for (int j = 0; j < 4; j++) {
    int row = wn * 64 + j * 16 + frow;
    offB[j] = row * 32 + ((fg ^ ((row ^ (row >> 2)) & 3)) << 3);
  }
  const int srow = tid >> 2;
  const int soff = (((tid & 3) ^ ((srow ^ (srow >> 2)) & 3)) << 3);
  const u16* Abase = A + (long)bm * 256 * KDIM;
  const u16* Bbase = Bt + (long)bn * 256 * KDIM;

  f32x4 acc[4][4];
#pragma unroll
  for (int m = 0; m < 4; m++)
#pragma unroll
    for (int n = 0; n < 4; n++) acc[m][n] = (f32x4)0.0f;

  auto STAGE = [&](const u16* gb, int kcol, int slot) {
    gld_lds16(gb + (long)srow * KDIM + kcol + soff, &smem[slot + w * 512]);
  };

  s16x8 af[2], bf[4];

  STAGE(Abase, 0,  SA0_); STAGE(Bbase, 0, SB0_); STAGE(Bbase, 32, SB1_);
  asm volatile("s_waitcnt vmcnt(1)" ::: "memory");
  asm volatile("s_barrier" ::: "memory");

#pragma unroll 1
  for (int t = 0; t < 16; t++) {
    const int cur = t * 64;
    const int nxt = ((t + 1) & 15) * 64;   // wraps harmlessly on last iter
    // ---- P1: (k0, mh0) ----
#pragma unroll
    for (int n = 0; n < 4; n++) bf[n] = *(const s16x8*)&smem[SB0_ + offB[n]];
#pragma unroll
    for (int m = 0; m < 2; m++) af[m] = *(const s16x8*)&smem[SA0_ + offA[m]];
    STAGE(Abase, cur + 32, SA1_);
    asm volatile("s_barrier" ::: "memory");
    __builtin_amdgcn_s_setprio(1);
#pragma unroll
    for (int m = 0; m < 2; m++)
#pragma unroll
      for (int n = 0; n < 4; n++) acc[m][n] = MFMA_BF16(af[m], bf[n], acc[m][n]);
    __builtin_amdgcn_s_setprio(0);
    asm volatile("s_waitcnt vmcnt(2)" ::: "memory");
    asm volatile("s_barrier" ::: "memory");
    // ---- P2: (k0, mh1) ----
#pragma unroll
    for (int m = 0; m < 2; m++) af[m] = *(const s16x8*)&smem[SA0_ + offA[2 + m]];
    STAGE(Bbase, nxt, SB0_);
    asm volatile("s_barrier" ::: "memory");
    __builtin_amdgcn_s_setprio(1);
#pragma unroll
    for (int m = 0; m < 2; m++)
#pragma unroll
      for (int n = 0; n < 4; n++) acc[2 + m][n] = MFMA_BF16(af[m], bf[n], acc[2 + m][n]);
    __builtin_amdgcn_s_setprio(0);
    asm volatile("s_waitcnt vmcnt(1)" ::: "memory");
    asm volatile("s_barrier" ::: "memory");
    // ---- P3: (k1, mh0) ----
#pragma unroll
    for (int n = 0; n < 4; n++) bf[n] = *(const s16x8*)&smem[SB1_ + offB[n]];
#pragma unroll
    for (int m = 0; m < 2; m++) af[m] = *(const s16x8*)&smem[SA1_ + offA[m]];
    STAGE(Abase, nxt, SA0_);
    asm volatile("s_barrier" ::: "memory");
    __builtin_amdgcn_s_setprio(1);
#pragma unroll
    for (int m = 0; m < 2; m++)
#pragma unroll
      for (int n = 0; n < 4; n++) acc[m][n] = MFMA_BF16(af[m], bf[n], acc[m][n]);
    __builtin_amdgcn_s_setprio(0);
    asm volatile("s_waitcnt vmcnt(2)" ::: "memory");
    asm volatile("s_barrier" ::: "memory");
    // ---- P4: (k1, mh1) ----
#pragma unroll
    for (int m = 0; m < 2; m++) af[m] = *(const s16x8*)&smem[SA1_ + offA[2 + m]];
    STAGE(Bbase, nxt + 32, SB1_);
    asm volatile("s_barrier" ::: "memory");
    __builtin_amdgcn_s_setprio(1);
#pragma unroll
    for (int m = 0; m < 2; m++)
#pragma unroll
      for (int n = 0; n < 4; n++) acc[2 + m][n] = MFMA_BF16(af[m], bf[n], acc[2 + m][n]);
    __builtin_amdgcn_s_setprio(0);
    asm volatile("s_waitcnt vmcnt(2)" ::: "memory");
    asm volatile("s_barrier" ::: "memory");
  }

  asm volatile("s_waitcnt vmcnt(0) lgkmcnt(0)" ::: "memory");
  asm volatile("s_barrier" ::: "memory");

  const int Mbase = bm * 256 + wm * 64;   // wave owns 64 rows

  if (!out_f32) {
    const int g = bn * 256 + wn * 64;      // wave's global col slab = one head
    const int part = g >> 10;              // 0=Q 1=K 2=V
    const int head = (g & 1023) >> 6;
    const float* bias = (part == 0) ? b0 : ((part == 1) ? b1 : b2);
    const float qs = (part == 0) ? QSCALE : 1.0f;   // fold score scale into Q
    float bv[4];
#pragma unroll
    for (int n = 0; n < 4; n++) bv[n] = bias[(g & 1023) + n * 16 + frow];

    if (part == 2) {
      // ---- V: [32][40]-u16 transpose bounce, 4 sub-passes (s-half x d-half) ----
      u16* vbuf = &smem[w * 2048];         // 2.5 KB used of 4 KB/wave
      const int batch = Mbase >> 12;
      u16* dstb = Vt + ((long)(batch * 16 + head)) * BHSTRIDE;
#pragma unroll
      for (int mf2 = 0; mf2 < 2; mf2++) {
        const int s0 = (Mbase & 4095) + mf2 * 32;
#pragma unroll
        for (int dh = 0; dh < 2; dh++) {
#pragma unroll
          for (int half = 0; half < 2; half++) {
            const int mf = mf2 * 2 + half;
#pragma unroll
            for (int nn = 0; nn < 2; nn++) {
              const int n = dh * 2 + nn;
              const int dloc = nn * 16 + frow;
#pragma unroll
              for (int r = 0; r < 4; r++)
                vbuf[dloc * 40 + half * 16 + 4 * fg + r] = f2b(acc[mf][n][r] + bv[n]);
            }
          }
          asm volatile("s_waitcnt lgkmcnt(0)" ::: "memory");
          __builtin_amdgcn_sched_barrier(0);
#pragma unroll
          for (int i = 0; i < 2; i++) {
            const int dloc = i * 16 + (lane >> 2);
            const int sl = lane & 3;
            s16x8 v = *(const s16x8*)&vbuf[dloc * 40 + sl * 8];
            *(s16x8*)(dstb + (long)(dh * 32 + dloc) * S_LEN + s0 + sl * 8) = v;
          }
          asm volatile("s_waitcnt lgkmcnt(0)" ::: "memory");
          __builtin_amdgcn_sched_barrier(0);
        }
      }
    } else {
      // ---- Q/K: swizzled wave-private bounce -> coalesced b128 stores
      u16* buf = &smem[w * 2048];            // 4 KB/wave x16 = 64 KB
#pragma unroll
      for (int mf2 = 0; mf2 < 2; mf2++) {
#pragma unroll
        for (int half = 0; half < 2; half++) {
          const int mf = mf2 * 2 + half;
#pragma unroll
          for (int n = 0; n < 4; n++)
#pragma unroll
            for (int r = 0; r < 4; r++) {
              int row32 = half * 16 + 4 * fg + r;
              int col = n * 16 + frow;
              buf[row32 * 64 + (((col >> 3) ^ (row32 & 7)) << 3) + (col & 7)] =
                  f2b((acc[mf][n][r] + bv[n]) * qs);
            }
        }
        asm volatile("s_waitcnt lgkmcnt(0)" ::: "memory");
        __builtin_amdgcn_sched_barrier(0);
        const int s0 = Mbase + mf2 * 32;
#pragma unroll
        for (int i = 0; i < 4; i++) {
          int flat = lane + 64 * i;
          int row32 = flat >> 3, ch = flat & 7;
          s16x8 v = *(const s16x8*)&buf[row32 * 64 + ((ch ^ (row32 & 7)) << 3)];
          int s = s0 + row32;
          u16* dst = (part == 0)
              ? (Qb + (long)s * 1024 + head * 64 + ch * 8)
              : (Kp + ((long)(s >> 12) * 16 + head) * BHSTRIDE + (long)(s & 4095) * 64 + ch * 8);
          *(s16x8*)dst = v;
        }
        asm volatile("s_waitcnt lgkmcnt(0)" ::: "memory");
        __builtin_amdgcn_sched_barrier(0);
      }
    }
  } else {
    // ---- f32 writer (gemm2): swizzled pitch-64 f32 bounce ----
    float* fbuf = (float*)&smem[w * 2048];   // [16][64] f32, 4 KB/wave
    const long crow0 = (long)Mbase * N + bn * 256 + wn * 64;
#pragma unroll
    for (int mf = 0; mf < 4; mf++) {
#pragma unroll
      for (int n = 0; n < 4; n++) {
        float bvv = b0[(bn * 256 + wn * 64 + n * 16 + frow) & 1023];
#pragma unroll
        for (int r = 0; r < 4; r++) {
          int row = 4 * fg + r;
          int o = 4 * n + (frow >> 2);
          fbuf[row * 64 + ((o ^ (row & 7)) << 2) + (frow & 3)] = acc[mf][n][r] + bvv;
        }
      }
      asm volatile("s_waitcnt lgkmcnt(0)" ::: "memory");
      __builtin_amdgcn_sched_barrier(0);
#pragma unroll
      for (int i = 0; i < 4; i++) {
        int flat = lane + 64 * i;
        int row = flat >> 4, oct = lane & 15;
        float4 v = *(const float4*)&fbuf[row * 64 + ((oct ^ (row & 7)) << 2)];
        *(float4*)((float*)Cp + crow0 + (long)(mf * 16 + row) * N + oct * 4) = v;
      }
      asm volatile("s_waitcnt lgkmcnt(0)" ::: "memory");
      __builtin_amdgcn_sched_barrier(0);
    }
  }
}

// ---------------- local attention (unchanged from r13) ----------------
#define QBLK 128

__global__ __launch_bounds__(256) void attn_kernel(const u16* __restrict__ Qb,
                                                   const u16* __restrict__ Kp,
                                                   const u16* __restrict__ Vt,
                                                   u16* __restrict__ Oa) {
  __shared__ __align__(16) u16 smem[16384];   // lK[2][64][64] + lV[2][64][64] = 32KB

  const int tid = threadIdx.x;
  const int w = tid >> 6, lane = tid & 63;
  const int frow = lane & 15, fg = lane >> 4;

  const int nq = S_LEN / QBLK;             // 32
  int bid = (int)blockIdx.x;
  bid = (bid & 7) * ((NB * NH * nq) >> 3) + (bid >> 3);   // XCD swizzle
  const int b = bid / (NH * nq);
  const int rem = bid % (NH * nq);
  const int h = rem / nq;
  const int qt = rem % nq;
  const int q0 = qt * QBLK;
  const int qw0 = q0 + 32 * w;

  const u16* Kpb = Kp + (long)(b * NH + h) * BHSTRIDE;
  const u16* Vtb = Vt + (long)(b * NH + h) * BHSTRIDE;

  s16x8 qf[2][2];
#pragma unroll
  for (int m = 0; m < 2; m++)
#pragma unroll
    for (int kk = 0; kk < 2; kk++)
      qf[m][kk] = *(const s16x8*)(Qb + (long)(b * S_LEN + qw0 + 16 * m + frow) * 1024 +
                                  h * 64 + kk * 32 + 8 * fg);

  f32x4 acc[2][4];
#pragma unroll
  for (int m = 0; m < 2; m++)
#pragma unroll
    for (int n = 0; n < 4; n++) acc[m][n] = (f32x4)0.0f;
  float mrow[2] = {-1e30f, -1e30f};
  float lrow[2] = {0.f, 0.f};

  const int r8 = lane >> 3;
  const int cs = ((lane & 7) ^ r8) << 3;     // swizzled source chunk (u16 units)

  auto STAGE = [&](int kvb, int bufi) {
#pragma unroll
    for (int pass = 0; pass < 2; pass++) {
      int rbase = pass * 32 + w * 8;
      gld_lds16(Kpb + (long)(kvb + rbase + r8) * 64 + cs, &smem[bufi * 4096 + rbase * 64]);
      gld_lds16(Vtb + (long)(rbase + r8) * S_LEN + kvb + cs, &smem[8192 + bufi * 4096 + rbase * 64]);
    }
  };

  const int tlo = (q0 == 0) ? 2 : 0;
  const int thi = (q0 == S_LEN - QBLK) ? 3 : 5;

  STAGE(q0 - 128 + 64 * tlo, 0);

#pragma unroll 1
  for (int t = tlo; t <= thi; t++) {
    const int cur = (t - tlo) & 1;
    const int kvb = q0 - 128 + 64 * t;
    if (t < thi) {
      STAGE(kvb + 64, cur ^ 1);
      asm volatile("s_waitcnt vmcnt(4)" ::: "memory");
    } else {
      asm volatile("s_waitcnt vmcnt(0)" ::: "memory");
    }
    asm volatile("s_barrier" ::: "memory");

    const bool active = (kvb + 63 >= qw0 - 128) && (kvb <= qw0 + 159);
    if (active) {
      const u16* lK = &smem[cur * 4096];
      const u16* lV = &smem[8192 + cur * 4096];
      const int delta = kvb - qw0;
      const bool interior = (delta >= -97) && (delta <= 65);
      f32x4 sfr[2][4];
#pragma unroll
      for (int m = 0; m < 2; m++)
#pragma unroll
        for (int n = 0; n < 4; n++) sfr[m][n] = (f32x4)0.0f;
#pragma unroll
      for (int kk = 0; kk < 2; kk++) {
        s16x8 kb[4];
#pragma unroll
        for (int n = 0; n < 4; n++)
          kb[n] = *(const s16x8*)&lK[(16 * n + frow) * 64 + (((fg + 4 * kk) ^ (frow & 7)) << 3)];
#pragma unroll
        for (int m = 0; m < 2; m++)
#pragma unroll
          for (int n = 0; n < 4; n++)
            sfr[m][n] = MFMA_BF16(kb[n], qf[m][kk], sfr[m][n]);
      }
      // ---- softmax in log2 domain ----
#pragma unroll
      for (int m = 0; m < 2; m++) {
        float tmax = -1e30f;
        if (interior) {
#pragma unroll
          for (int n = 0; n < 4; n++)
#pragma unroll
            for (int r = 0; r < 4; r++) tmax = fmaxf(tmax, sfr[m][n][r]);
        } else {
          const int dbase = kvb - (qw0 + 16 * m + frow) + 128 + 4 * fg;  // + 16n + r
#pragma unroll
          for (int n = 0; n < 4; n++)
#pragma unroll
            for (int r = 0; r < 4; r++) {
              bool valid = (unsigned)(dbase + 16 * n + r) <= 256u;
              float xv = valid ? sfr[m][n][r] : -1e30f;
              sfr[m][n][r] = xv;
              tmax = fmaxf(tmax, xv);
            }
        }
        tmax = fmaxf(tmax, __shfl_xor(tmax, 16));
        tmax = fmaxf(tmax, __shfl_xor(tmax, 32));
        if (!__all(tmax - mrow[m] <= THR2)) {
          float mnew = fmaxf(mrow[m], tmax);
          float al = exp2_fast(mrow[m] - mnew);
          mrow[m] = mnew;
          lrow[m] *= al;
          float a4[4];
#pragma unroll
          for (int r = 0; r < 4; r++) a4[r] = __shfl(al, 20 * fg + r);
#pragma unroll
          for (int nd = 0; nd < 4; nd++)
#pragma unroll
            for (int r = 0; r < 4; r++) acc[m][nd][r] *= a4[r];
        }
        float ps = 0.f;
#pragma unroll
        for (int n = 0; n < 4; n++)
#pragma unroll
          for (int r = 0; r < 4; r++) {
            float e = exp2_fast(sfr[m][n][r] - mrow[m]);   // masked: exp2(-huge) -> 0
            sfr[m][n][r] = e;
            ps += e;
          }
        ps += __shfl_xor(ps, 16);
        ps += __shfl_xor(ps, 32);
        lrow[m] += ps;
      }
      s16x8 pa[2][2];
#pragma unroll
      for (int m = 0; m < 2; m++)
#pragma unroll
        for (int kt = 0; kt < 2; kt++)
#pragma unroll
          for (int j = 0; j < 8; j++)
            pa[m][kt][j] = (short)f2b(sfr[m][2 * kt + (j >> 2)][j & 3]);
#pragma unroll
      for (int kt = 0; kt < 2; kt++)
#pragma unroll
        for (int nd = 0; nd < 4; nd++) {
          const int d = 16 * nd + frow;
          const int key = frow & 7;
          const int olo = (4 * kt + (fg >> 1)) ^ key;
          const int ohi = (4 * kt + 2 + (fg >> 1)) ^ key;
          s16x4 lo = *(const s16x4*)&lV[d * 64 + olo * 8 + (fg & 1) * 4];
          s16x4 hi = *(const s16x4*)&lV[d * 64 + ohi * 8 + (fg & 1) * 4];
          s16x8 vb;
          vb[0] = lo[0]; vb[1] = lo[1]; vb[2] = lo[2]; vb[3] = lo[3];
          vb[4] = hi[0]; vb[5] = hi[1]; vb[6] = hi[2]; vb[7] = hi[3];
#pragma unroll
          for (int m = 0; m < 2; m++)
            acc[m][nd] = MFMA_BF16(pa[m][kt], vb, acc[m][nd]);
        }
    }
    asm volatile("s_barrier" ::: "memory");
  }

  float i4[2][4];
#pragma unroll
  for (int m = 0; m < 2; m++) {
    float inv = 1.0f / lrow[m];
#pragma unroll
    for (int r = 0; r < 4; r++) i4[m][r] = __shfl(inv, 20 * fg + r);
  }
  u16* bb = &smem[w * 2048];   // [32][64] swizzled
#pragma unroll
  for (int m = 0; m < 2; m++)
#pragma unroll
    for (int nd = 0; nd < 4; nd++)
#pragma unroll
      for (int r = 0; r < 4; r++) {
        int row32 = 16 * m + 4 * fg + r;
        int col = 16 * nd + frow;
        bb[row32 * 64 + (((col >> 3) ^ (row32 & 7)) << 3) + (col & 7)] =
            f2b(acc[m][nd][r] * i4[m][r]);
      }
  asm volatile("s_waitcnt lgkmcnt(0)" ::: "memory");
  __builtin_amdgcn_sched_barrier(0);
  u16* Ob = Oa + ((long)(b * S_LEN + qw0)) * EMB + h * HD;
#pragma unroll
  for (int i = 0; i < 4; i++) {
    int flat = lane + 64 * i;
    int row32 = flat >> 3, ch = flat & 7;
    s16x8 v = *(const s16x8*)&bb[row32 * 64 + ((ch ^ (row32 & 7)) << 3)];
    *(s16x8*)(Ob + (long)row32 * EMB + ch * 8) = v;
  }
}

extern "C" void kernel_launch(void* const* d_in, const int* in_sizes, int n_in,
                              void* d_out, int out_size, void* d_ws, size_t ws_size,
                              hipStream_t stream) {
  const float* x  = (const float*)d_in[0];
  const float* Wq = (const float*)d_in[1];
  const float* bq = (const float*)d_in[2];
  const float* Wk = (const float*)d_in[3];
  const float* bk = (const float*)d_in[4];
  const float* Wv = (const float*)d_in[5];
  const float* bv = (const float*)d_in[6];
  const float* Wo = (const float*)d_in[7];
  const float* bo = (const float*)d_in[8];

  char* ws = (char*)d_ws;
  u16* xb   = (u16*)ws;  ws += (size_t)NROWS * EMB * 2;        // 32 MB
  u16* Wt   = (u16*)ws;  ws += (size_t)3 * EMB * EMB * 2;      // 6 MB
  u16* Wot  = (u16*)ws;  ws += (size_t)EMB * EMB * 2;          // 2 MB
  u16* Qbuf = (u16*)ws;  ws += (size_t)NROWS * EMB * 2;        // 32 MB
  u16* Kpb  = (u16*)ws;  ws += (size_t)NB * NH * BHSTRIDE * 2; // 32 MB
  u16* Vtb  = (u16*)ws;  ws += (size_t)NB * NH * BHSTRIDE * 2; // 32 MB
  u16* Oab  = (u16*)ws;  ws += (size_t)NROWS * EMB * 2;        // 32 MB

  cvt_x_kernel<<<(NROWS * EMB) / (256 * 8), 256, 0, stream>>>(x, xb);

  dim3 tg(EMB / 32, EMB / 32, 4);
  transpose_cvt4_kernel<<<tg, 256, 0, stream>>>(
      Wq, Wk, Wv, Wo, Wt, Wt + (size_t)EMB * EMB, Wt + (size_t)2 * EMB * EMB, Wot);

  gemm8p_kernel<<<(NROWS / 256) * (3 * EMB / 256), 1024, 0, stream>>>(
      xb, Wt, bq, bk, bv, nullptr, Qbuf, Kpb, Vtb, 3 * EMB, 0);

  attn_kernel<<<NB * NH * (S_LEN / QBLK), 256, 0, stream>>>(Qbuf, Kpb, Vtb, Oab);

  gemm8p_kernel<<<(NROWS / 256) * (EMB / 256), 1024, 0, stream>>>(
      Oab, Wot, bo, bo, bo, d_out, nullptr, nullptr, nullptr, EMB, 1);
}

// Round 15
// 1467.424 us; speedup vs baseline: 1.5088x; 1.5088x over previous
//
#include <hip/hip_runtime.h>
#include <hip/hip_bf16.h>
#include <type_traits>
#include <math.h>

typedef unsigned short u16;
typedef __attribute__((ext_vector_type(8))) short  s16x8;
typedef __attribute__((ext_vector_type(4))) short  s16x4;
typedef __attribute__((ext_vector_type(8))) __bf16 b16x8;
typedef __attribute__((ext_vector_type(4))) float  f32x4;

#define S_LEN 4096
#define NB    4
#define EMB   1024
#define NH    16
#define HD    64
#define NROWS (NB * S_LEN)   // 16384
#define KDIM  1024
#define BHSTRIDE (S_LEN * HD)   // 262144 u16 per (b,h) for Kp / Vt
#define QSCALE 0.18033688f      // 0.125 * log2(e): scores land in log2-domain
#define THR2   11.5429f         // defer-max threshold, 8 nats in log2 units

static __device__ __forceinline__ u16 f2b(float f) {
  __hip_bfloat16 h = __float2bfloat16(f);
  return __builtin_bit_cast(u16, h);
}

static __device__ __forceinline__ float exp2_fast(float x) {
#if __has_builtin(__builtin_amdgcn_exp2f)
  return __builtin_amdgcn_exp2f(x);   // raw v_exp_f32
#else
  return exp2f(x);
#endif
}

// ---- MFMA shim ----
template <typename T, typename = void>
struct mfma_takes : std::false_type {};
template <typename T>
struct mfma_takes<T, std::void_t<decltype(__builtin_amdgcn_mfma_f32_16x16x32_bf16(
    std::declval<T>(), std::declval<T>(), std::declval<f32x4>(), 0, 0, 0))>> : std::true_type {};

template <typename AB>
static __device__ __forceinline__ f32x4 mfma_any(AB a, AB b, f32x4 c) {
  return __builtin_amdgcn_mfma_f32_16x16x32_bf16(a, b, c, 0, 0, 0);
}

template <typename S8 = s16x8, typename B8 = b16x8>
static __device__ __forceinline__ f32x4 MFMA_BF16(s16x8 a, s16x8 b, f32x4 c) {
  if constexpr (mfma_takes<S8>::value)
    return mfma_any<S8>(__builtin_bit_cast(S8, a), __builtin_bit_cast(S8, b), c);
  else
    return mfma_any<B8>(__builtin_bit_cast(B8, a), __builtin_bit_cast(B8, b), c);
}

static __device__ __forceinline__ void gld_lds16(const void* g, void* l) {
  __builtin_amdgcn_global_load_lds((const __attribute__((address_space(1))) void*)g,
                                   (__attribute__((address_space(3))) void*)l, 16, 0, 0);
}

// ---------------- fp32 -> bf16 conversion (x) ----------------
__global__ __launch_bounds__(256) void cvt_x_kernel(const float* __restrict__ in,
                                                    u16* __restrict__ out) {
  long i = ((long)blockIdx.x * 256 + threadIdx.x) * 8;
  float4 a = *(const float4*)(in + i);
  float4 b = *(const float4*)(in + i + 4);
  s16x8 o;
  o[0] = (short)f2b(a.x); o[1] = (short)f2b(a.y); o[2] = (short)f2b(a.z); o[3] = (short)f2b(a.w);
  o[4] = (short)f2b(b.x); o[5] = (short)f2b(b.y); o[6] = (short)f2b(b.z); o[7] = (short)f2b(b.w);
  *(s16x8*)(out + i) = o;
}

// ---------------- transpose + convert 4 x W, fused ----------------
__global__ __launch_bounds__(256) void transpose_cvt4_kernel(
    const float* __restrict__ W0, const float* __restrict__ W1,
    const float* __restrict__ W2, const float* __restrict__ W3,
    u16* __restrict__ D0, u16* __restrict__ D1, u16* __restrict__ D2, u16* __restrict__ D3) {
  __shared__ float tile[32][33];
  const float* W; u16* D;
  switch (blockIdx.z) {
    case 0:  W = W0; D = D0; break;
    case 1:  W = W1; D = D1; break;
    case 2:  W = W2; D = D2; break;
    default: W = W3; D = D3; break;
  }
  int n0 = blockIdx.x * 32, k0 = blockIdx.y * 32;
  int tx = threadIdx.x & 31, ty = threadIdx.x >> 5;
#pragma unroll
  for (int i = ty; i < 32; i += 8)
    tile[i][tx] = W[(long)(k0 + i) * EMB + n0 + tx];
  __syncthreads();
#pragma unroll
  for (int i = ty; i < 32; i += 8)
    D[(long)(n0 + i) * EMB + k0 + tx] = f2b(tile[tx][i]);
}

// ========== 256x256 GEMM, 8 waves, 64KB LDS (4 slots) -> 2 blocks/CU ==========
// Slots (u16): SA0=0 SA1=8192 SB0=16384 SB1=24576 (16KB each; A/B half-K-tiles).
// Tile t: P1 reads SA0(mh0)+SB0 | stage SA1<-A(t,+32);  P2 reads SA0(mh1) | stage SB0'<-B(t+1,+0)
//         P3 reads SA1(mh0)+SB1 | stage SA0'<-A(t+1,+0); P4 reads SA1(mh1)| stage SB1'<-B(t+1,+32)
// Waits: vmcnt(2) ONLY at P2-end and P4-end (2 loads/stage):
//   P2-end: outstanding {SB1(2,old),SA1(2),SB0'(2)} -> drains SB1,SA1 (read P3) keep SB0'
//   P4-end: outstanding {SB0'(2),SA0'(2),SB1'(2)} -> drains SB0',SA0' (read next-P1) keep SB1'
// Leads: SB0',SB1' = 2-phase; SA1,SA0' = 1-phase (absorbed by co-resident 2nd block).
// WAR: each slot restaged >= 1 barrier after its last read (checked per-phase).
// Prologue: SA0,SB0,SB1 (6 loads); vm(2) drains SA0,SB0; bar.
#define SA0_ 0
#define SA1_ 8192
#define SB0_ 16384
#define SB1_ 24576

__global__ __launch_bounds__(512, 4) void gemm8p_kernel(
    const u16* __restrict__ A, const u16* __restrict__ Bt,
    const float* __restrict__ b0, const float* __restrict__ b1, const float* __restrict__ b2,
    void* __restrict__ Cp, u16* __restrict__ Qb, u16* __restrict__ Kp, u16* __restrict__ Vt,
    int N, int out_f32) {
  __shared__ __align__(16) u16 smem[32768];   // 64 KiB
  const int tid = threadIdx.x;
  const int w = tid >> 6, lane = tid & 63;
  const int wm = w >> 2, wn = w & 3;
  const int frow = lane & 15, fg = lane >> 4;

  const int nwg = gridDim.x;
  const int bid = ((int)blockIdx.x & 7) * (nwg >> 3) + ((int)blockIdx.x >> 3);
  const int nbn = N >> 8;
  const int bm = bid / nbn, bn = bid % nbn;

  int offA[8];
#pragma unroll
  for (int j = 0; j < 8; j++) {
    int row = wm * 128 + j * 16 + frow;
    offA[j] = row * 32 + ((fg ^ ((row ^ (row >> 2)) & 3)) << 3);
  }
  int offB[4];
#pragma unroll
  for (int j = 0; j < 4; j++) {
    int row = wn * 64 + j * 16 + frow;
    offB[j] = row * 32 + ((fg ^ ((row ^ (row >> 2)) & 3)) << 3);
  }
  int srow[2], soff[2];
#pragma unroll
  for (int L = 0; L < 2; L++) {
    int lin = L * 512 + tid;
    int r = lin >> 2;
    srow[L] = r;
    soff[L] = (((lin & 3) ^ ((r ^ (r >> 2)) & 3)) << 3);
  }
  const u16* Abase = A + (long)bm * 256 * KDIM;
  const u16* Bbase = Bt + (long)bn * 256 * KDIM;

  f32x4 acc[8][4];
#pragma unroll
  for (int m = 0; m < 8; m++)
#pragma unroll
    for (int n = 0; n < 4; n++) acc[m][n] = (f32x4)0.0f;

  auto STAGE = [&](const u16* gb, int kcol, int slot) {
#pragma unroll
    for (int L = 0; L < 2; L++)
      gld_lds16(gb + (long)srow[L] * KDIM + kcol + soff[L],
                &smem[slot + (L * 512 + w * 64) * 8]);
  };

  s16x8 af[4], bf[4];

  STAGE(Abase, 0, SA0_); STAGE(Bbase, 0, SB0_); STAGE(Bbase, 32, SB1_);
  asm volatile("s_waitcnt vmcnt(2)" ::: "memory");
  asm volatile("s_barrier" ::: "memory");

#define PHASE(ASL, BSL, mh, RDB, GB, KCOL, SLOT, DOVM)                        \
  {                                                                           \
    if (RDB) {                                                                \
      _Pragma("unroll") for (int n = 0; n < 4; n++)                           \
        bf[n] = *(const s16x8*)&smem[BSL + offB[n]];                          \
    }                                                                         \
    _Pragma("unroll") for (int m = 0; m < 4; m++)                             \
      af[m] = *(const s16x8*)&smem[ASL + offA[(mh) * 4 + m]];                 \
    STAGE(GB, KCOL, SLOT);                                                    \
    asm volatile("s_barrier" ::: "memory");                                   \
    __builtin_amdgcn_s_setprio(1);                                            \
    _Pragma("unroll") for (int m = 0; m < 4; m++)                             \
      _Pragma("unroll") for (int n = 0; n < 4; n++)                           \
        acc[(mh) * 4 + m][n] = MFMA_BF16(af[m], bf[n], acc[(mh) * 4 + m][n]); \
    __builtin_amdgcn_s_setprio(0);                                            \
    if (DOVM) asm volatile("s_waitcnt vmcnt(2)" ::: "memory");                \
    asm volatile("s_barrier" ::: "memory");                                   \
  }

#pragma unroll 1
  for (int t = 0; t < 16; t++) {
    const int cur = t * 64;
    const int nxt = ((t + 1) & 15) * 64;   // wraps harmlessly on last iter (data unused)
    PHASE(SA0_, SB0_, 0, 1, Abase, cur + 32, SA1_, 0)
    PHASE(SA0_, SB0_, 1, 0, Bbase, nxt,      SB0_, 1)
    PHASE(SA1_, SB1_, 0, 1, Abase, nxt,      SA0_, 0)
    PHASE(SA1_, SB1_, 1, 0, Bbase, nxt + 32, SB1_, 1)
  }
#undef PHASE

  asm volatile("s_waitcnt vmcnt(0) lgkmcnt(0)" ::: "memory");
  asm volatile("s_barrier" ::: "memory");

  const int Mbase = bm * 256 + wm * 128;

  if (!out_f32) {
    const int g = bn * 256 + wn * 64;      // wave's global col slab = one head
    const int part = g >> 10;              // 0=Q 1=K 2=V
    const int head = (g & 1023) >> 6;
    const float* bias = (part == 0) ? b0 : ((part == 1) ? b1 : b2);
    const float qs = (part == 0) ? QSCALE : 1.0f;   // fold score scale into Q
    float bv[4];
#pragma unroll
    for (int n = 0; n < 4; n++) bv[n] = bias[(g & 1023) + n * 16 + frow];

    if (part == 2) {
      // ---- V: per-wave [64][40]-u16 transpose bounce -> full-sector coalesced stores.
      u16* vbuf = &smem[w * 2560];         // 5 KB/wave x8 = 40 KB <= 64 KB
      const int batch = Mbase >> 12;
      u16* dstb = Vt + ((long)(batch * 16 + head)) * BHSTRIDE;
#pragma unroll
      for (int mf2 = 0; mf2 < 4; mf2++) {
        const int s0 = (Mbase & 4095) + mf2 * 32;
#pragma unroll
        for (int half = 0; half < 2; half++) {
          const int mf = mf2 * 2 + half;
#pragma unroll
          for (int n = 0; n < 4; n++) {
            const int d = n * 16 + frow;
#pragma unroll
            for (int r = 0; r < 4; r++)
              vbuf[d * 40 + half * 16 + 4 * fg + r] = f2b(acc[mf][n][r] + bv[n]);
          }
        }
        asm volatile("s_waitcnt lgkmcnt(0)" ::: "memory");
        __builtin_amdgcn_sched_barrier(0);
#pragma unroll
        for (int i = 0; i < 4; i++) {
          const int d = i * 16 + (lane >> 2);
          const int sl = lane & 3;
          s16x8 v = *(const s16x8*)&vbuf[d * 40 + sl * 8];
          *(s16x8*)(dstb + (long)d * S_LEN + s0 + sl * 8) = v;
        }
        asm volatile("s_waitcnt lgkmcnt(0)" ::: "memory");
        __builtin_amdgcn_sched_barrier(0);
      }
    } else {
      // ---- Q/K: swizzled wave-private bounce -> coalesced b128 stores
      u16* buf = &smem[w * 2048];            // 4 KB/wave x8 = 32 KB
#pragma unroll
      for (int mf2 = 0; mf2 < 4; mf2++) {
#pragma unroll
        for (int half = 0; half < 2; half++) {
          const int mf = mf2 * 2 + half;
#pragma unroll
          for (int n = 0; n < 4; n++)
#pragma unroll
            for (int r = 0; r < 4; r++) {
              int row32 = half * 16 + 4 * fg + r;
              int col = n * 16 + frow;
              buf[row32 * 64 + (((col >> 3) ^ (row32 & 7)) << 3) + (col & 7)] =
                  f2b((acc[mf][n][r] + bv[n]) * qs);
            }
        }
        asm volatile("s_waitcnt lgkmcnt(0)" ::: "memory");
        __builtin_amdgcn_sched_barrier(0);
        const int s0 = Mbase + mf2 * 32;
#pragma unroll
        for (int i = 0; i < 4; i++) {
          int flat = lane + 64 * i;
          int row32 = flat >> 3, ch = flat & 7;
          s16x8 v = *(const s16x8*)&buf[row32 * 64 + ((ch ^ (row32 & 7)) << 3)];
          int s = s0 + row32;
          u16* dst = (part == 0)
              ? (Qb + (long)s * 1024 + head * 64 + ch * 8)
              : (Kp + ((long)(s >> 12) * 16 + head) * BHSTRIDE + (long)(s & 4095) * 64 + ch * 8);
          *(s16x8*)dst = v;
        }
        asm volatile("s_waitcnt lgkmcnt(0)" ::: "memory");
        __builtin_amdgcn_sched_barrier(0);
      }
    }
  } else {
    // ---- f32 writer (gemm2): swizzled pitch-64 f32 bounce ----
    float* fbuf = (float*)&smem[w * 2048];   // [16][64] f32, 4 KB/wave x8 = 32 KB
    const long crow0 = (long)Mbase * N + bn * 256 + wn * 64;
#pragma unroll
    for (int mf = 0; mf < 8; mf++) {
#pragma unroll
      for (int n = 0; n < 4; n++) {
        float bvv = b0[(bn * 256 + wn * 64 + n * 16 + frow) & 1023];
#pragma unroll
        for (int r = 0; r < 4; r++) {
          int row = 4 * fg + r;
          int o = 4 * n + (frow >> 2);
          fbuf[row * 64 + ((o ^ (row & 7)) << 2) + (frow & 3)] = acc[mf][n][r] + bvv;
        }
      }
      asm volatile("s_waitcnt lgkmcnt(0)" ::: "memory");
      __builtin_amdgcn_sched_barrier(0);
#pragma unroll
      for (int i = 0; i < 4; i++) {
        int flat = lane + 64 * i;
        int row = flat >> 4, oct = lane & 15;
        float4 v = *(const float4*)&fbuf[row * 64 + ((oct ^ (row & 7)) << 2)];
        *(float4*)((float*)Cp + crow0 + (long)(mf * 16 + row) * N + oct * 4) = v;
      }
      asm volatile("s_waitcnt lgkmcnt(0)" ::: "memory");
      __builtin_amdgcn_sched_barrier(0);
    }
  }
}

// ---------------- local attention (unchanged from r13) ----------------
#define QBLK 128

__global__ __launch_bounds__(256) void attn_kernel(const u16* __restrict__ Qb,
                                                   const u16* __restrict__ Kp,
                                                   const u16* __restrict__ Vt,
                                                   u16* __restrict__ Oa) {
  __shared__ __align__(16) u16 smem[16384];   // lK[2][64][64] + lV[2][64][64] = 32KB

  const int tid = threadIdx.x;
  const int w = tid >> 6, lane = tid & 63;
  const int frow = lane & 15, fg = lane >> 4;

  const int nq = S_LEN / QBLK;             // 32
  int bid = (int)blockIdx.x;
  bid = (bid & 7) * ((NB * NH * nq) >> 3) + (bid >> 3);   // XCD swizzle
  const int b = bid / (NH * nq);
  const int rem = bid % (NH * nq);
  const int h = rem / nq;
  const int qt = rem % nq;
  const int q0 = qt * QBLK;
  const int qw0 = q0 + 32 * w;

  const u16* Kpb = Kp + (long)(b * NH + h) * BHSTRIDE;
  const u16* Vtb = Vt + (long)(b * NH + h) * BHSTRIDE;

  s16x8 qf[2][2];
#pragma unroll
  for (int m = 0; m < 2; m++)
#pragma unroll
    for (int kk = 0; kk < 2; kk++)
      qf[m][kk] = *(const s16x8*)(Qb + (long)(b * S_LEN + qw0 + 16 * m + frow) * 1024 +
                                  h * 64 + kk * 32 + 8 * fg);

  f32x4 acc[2][4];
#pragma unroll
  for (int m = 0; m < 2; m++)
#pragma unroll
    for (int n = 0; n < 4; n++) acc[m][n] = (f32x4)0.0f;
  float mrow[2] = {-1e30f, -1e30f};
  float lrow[2] = {0.f, 0.f};

  const int r8 = lane >> 3;
  const int cs = ((lane & 7) ^ r8) << 3;     // swizzled source chunk (u16 units)

  auto STAGE = [&](int kvb, int bufi) {
#pragma unroll
    for (int pass = 0; pass < 2; pass++) {
      int rbase = pass * 32 + w * 8;
      gld_lds16(Kpb + (long)(kvb + rbase + r8) * 64 + cs, &smem[bufi * 4096 + rbase * 64]);
      gld_lds16(Vtb + (long)(rbase + r8) * S_LEN + kvb + cs, &smem[8192 + bufi * 4096 + rbase * 64]);
    }
  };

  const int tlo = (q0 == 0) ? 2 : 0;
  const int thi = (q0 == S_LEN - QBLK) ? 3 : 5;

  STAGE(q0 - 128 + 64 * tlo, 0);

#pragma unroll 1
  for (int t = tlo; t <= thi; t++) {
    const int cur = (t - tlo) & 1;
    const int kvb = q0 - 128 + 64 * t;
    if (t < thi) {
      STAGE(kvb + 64, cur ^ 1);
      asm volatile("s_waitcnt vmcnt(4)" ::: "memory");
    } else {
      asm volatile("s_waitcnt vmcnt(0)" ::: "memory");
    }
    asm volatile("s_barrier" ::: "memory");

    const bool active = (kvb + 63 >= qw0 - 128) && (kvb <= qw0 + 159);
    if (active) {
      const u16* lK = &smem[cur * 4096];
      const u16* lV = &smem[8192 + cur * 4096];
      const int delta = kvb - qw0;
      const bool interior = (delta >= -97) && (delta <= 65);
      f32x4 sfr[2][4];
#pragma unroll
      for (int m = 0; m < 2; m++)
#pragma unroll
        for (int n = 0; n < 4; n++) sfr[m][n] = (f32x4)0.0f;
#pragma unroll
      for (int kk = 0; kk < 2; kk++) {
        s16x8 kb[4];
#pragma unroll
        for (int n = 0; n < 4; n++)
          kb[n] = *(const s16x8*)&lK[(16 * n + frow) * 64 + (((fg + 4 * kk) ^ (frow & 7)) << 3)];
#pragma unroll
        for (int m = 0; m < 2; m++)
#pragma unroll
          for (int n = 0; n < 4; n++)
            sfr[m][n] = MFMA_BF16(kb[n], qf[m][kk], sfr[m][n]);
      }
      // ---- softmax in log2 domain ----
#pragma unroll
      for (int m = 0; m < 2; m++) {
        float tmax = -1e30f;
        if (interior) {
#pragma unroll
          for (int n = 0; n < 4; n++)
#pragma unroll
            for (int r = 0; r < 4; r++) tmax = fmaxf(tmax, sfr[m][n][r]);
        } else {
          const int dbase = kvb - (qw0 + 16 * m + frow) + 128 + 4 * fg;  // + 16n + r
#pragma unroll
          for (int n = 0; n < 4; n++)
#pragma unroll
            for (int r = 0; r < 4; r++) {
              bool valid = (unsigned)(dbase + 16 * n + r) <= 256u;
              float xv = valid ? sfr[m][n][r] : -1e30f;
              sfr[m][n][r] = xv;
              tmax = fmaxf(tmax, xv);
            }
        }
        tmax = fmaxf(tmax, __shfl_xor(tmax, 16));
        tmax = fmaxf(tmax, __shfl_xor(tmax, 32));
        if (!__all(tmax - mrow[m] <= THR2)) {
          float mnew = fmaxf(mrow[m], tmax);
          float al = exp2_fast(mrow[m] - mnew);
          mrow[m] = mnew;
          lrow[m] *= al;
          float a4[4];
#pragma unroll
          for (int r = 0; r < 4; r++) a4[r] = __shfl(al, 20 * fg + r);
#pragma unroll
          for (int nd = 0; nd < 4; nd++)
#pragma unroll
            for (int r = 0; r < 4; r++) acc[m][nd][r] *= a4[r];
        }
        float ps = 0.f;
#pragma unroll
        for (int n = 0; n < 4; n++)
#pragma unroll
          for (int r = 0; r < 4; r++) {
            float e = exp2_fast(sfr[m][n][r] - mrow[m]);   // masked: exp2(-huge) -> 0
            sfr[m][n][r] = e;
            ps += e;
          }
        ps += __shfl_xor(ps, 16);
        ps += __shfl_xor(ps, 32);
        lrow[m] += ps;
      }
      s16x8 pa[2][2];
#pragma unroll
      for (int m = 0; m < 2; m++)
#pragma unroll
        for (int kt = 0; kt < 2; kt++)
#pragma unroll
          for (int j = 0; j < 8; j++)
            pa[m][kt][j] = (short)f2b(sfr[m][2 * kt + (j >> 2)][j & 3]);
#pragma unroll
      for (int kt = 0; kt < 2; kt++)
#pragma unroll
        for (int nd = 0; nd < 4; nd++) {
          const int d = 16 * nd + frow;
          const int key = frow & 7;
          const int olo = (4 * kt + (fg >> 1)) ^ key;
          const int ohi = (4 * kt + 2 + (fg >> 1)) ^ key;
          s16x4 lo = *(const s16x4*)&lV[d * 64 + olo * 8 + (fg & 1) * 4];
          s16x4 hi = *(const s16x4*)&lV[d * 64 + ohi * 8 + (fg & 1) * 4];
          s16x8 vb;
          vb[0] = lo[0]; vb[1] = lo[1]; vb[2] = lo[2]; vb[3] = lo[3];
          vb[4] = hi[0]; vb[5] = hi[1]; vb[6] = hi[2]; vb[7] = hi[3];
#pragma unroll
          for (int m = 0; m < 2; m++)
            acc[m][nd] = MFMA_BF16(pa[m][kt], vb, acc[m][nd]);
        }
    }
    asm volatile("s_barrier" ::: "memory");
  }

  float i4[2][4];
#pragma unroll
  for (int m = 0; m < 2; m++) {
    float inv = 1.0f / lrow[m];
#pragma unroll
    for (int r = 0; r < 4; r++) i4[m][r] = __shfl(inv, 20 * fg + r);
  }
  u16* bb = &smem[w * 2048];   // [32][64] swizzled
#pragma unroll
  for (int m = 0; m < 2; m++)
#pragma unroll
    for (int nd = 0; nd < 4; nd++)
#pragma unroll
      for (int r = 0; r < 4; r++) {
        int row32 = 16 * m + 4 * fg + r;
        int col = 16 * nd + frow;
        bb[row32 * 64 + (((col >> 3) ^ (row32 & 7)) << 3) + (col & 7)] =
            f2b(acc[m][nd][r] * i4[m][r]);
      }
  asm volatile("s_waitcnt lgkmcnt(0)" ::: "memory");
  __builtin_amdgcn_sched_barrier(0);
  u16* Ob = Oa + ((long)(b * S_LEN + qw0)) * EMB + h * HD;
#pragma unroll
  for (int i = 0; i < 4; i++) {
    int flat = lane + 64 * i;
    int row32 = flat >> 3, ch = flat & 7;
    s16x8 v = *(const s16x8*)&bb[row32 * 64 + ((ch ^ (row32 & 7)) << 3)];
    *(s16x8*)(Ob + (long)row32 * EMB + ch * 8) = v;
  }
}

extern "C" void kernel_launch(void* const* d_in, const int* in_sizes, int n_in,
                              void* d_out, int out_size, void* d_ws, size_t ws_size,
                              hipStream_t stream) {
  const float* x  = (const float*)d_in[0];
  const float* Wq = (const float*)d_in[1];
  const float* bq = (const float*)d_in[2];
  const float* Wk = (const float*)d_in[3];
  const float* bk = (const float*)d_in[4];
  const float* Wv = (const float*)d_in[5];
  const float* bv = (const float*)d_in[6];
  const float* Wo = (const float*)d_in[7];
  const float* bo = (const float*)d_in[8];

  char* ws = (char*)d_ws;
  u16* xb   = (u16*)ws;  ws += (size_t)NROWS * EMB * 2;        // 32 MB
  u16* Wt   = (u16*)ws;  ws += (size_t)3 * EMB * EMB * 2;      // 6 MB
  u16* Wot  = (u16*)ws;  ws += (size_t)EMB * EMB * 2;          // 2 MB
  u16* Qbuf = (u16*)ws;  ws += (size_t)NROWS * EMB * 2;        // 32 MB
  u16* Kpb  = (u16*)ws;  ws += (size_t)NB * NH * BHSTRIDE * 2; // 32 MB
  u16* Vtb  = (u16*)ws;  ws += (size_t)NB * NH * BHSTRIDE * 2; // 32 MB
  u16* Oab  = (u16*)ws;  ws += (size_t)NROWS * EMB * 2;        // 32 MB

  cvt_x_kernel<<<(NROWS * EMB) / (256 * 8), 256, 0, stream>>>(x, xb);

  dim3 tg(EMB / 32, EMB / 32, 4);
  transpose_cvt4_kernel<<<tg, 256, 0, stream>>>(
      Wq, Wk, Wv, Wo, Wt, Wt + (size_t)EMB * EMB, Wt + (size_t)2 * EMB * EMB, Wot);

  gemm8p_kernel<<<(NROWS / 256) * (3 * EMB / 256), 512, 0, stream>>>(
      xb, Wt, bq, bk, bv, nullptr, Qbuf, Kpb, Vtb, 3 * EMB, 0);

  attn_kernel<<<NB * NH * (S_LEN / QBLK), 256, 0, stream>>>(Qbuf, Kpb, Vtb, Oab);

  gemm8p_kernel<<<(NROWS / 256) * (EMB / 256), 512, 0, stream>>>(
      Oab, Wot, bo, bo, bo, d_out, nullptr, nullptr, nullptr, EMB, 1);
}

// Round 16
// 238.005 us; speedup vs baseline: 9.3028x; 6.1655x over previous
//
#include <hip/hip_runtime.h>
#include <hip/hip_bf16.h>
#include <type_traits>
#include <math.h>

typedef unsigned short u16;
typedef __attribute__((ext_vector_type(8))) short  s16x8;
typedef __attribute__((ext_vector_type(4))) short  s16x4;
typedef __attribute__((ext_vector_type(8))) __bf16 b16x8;
typedef __attribute__((ext_vector_type(4))) float  f32x4;

#define S_LEN 4096
#define NB    4
#define EMB   1024
#define NH    16
#define HD    64
#define NROWS (NB * S_LEN)   // 16384
#define KDIM  1024
#define BHSTRIDE (S_LEN * HD)   // 262144 u16 per (b,h) for Kp / Vt
#define QSCALE 0.18033688f      // 0.125 * log2(e): scores land in log2-domain
#define THR2   11.5429f         // defer-max threshold, 8 nats in log2 units

static __device__ __forceinline__ u16 f2b(float f) {
  __hip_bfloat16 h = __float2bfloat16(f);
  return __builtin_bit_cast(u16, h);
}

static __device__ __forceinline__ float exp2_fast(float x) {
#if __has_builtin(__builtin_amdgcn_exp2f)
  return __builtin_amdgcn_exp2f(x);   // raw v_exp_f32
#else
  return exp2f(x);
#endif
}

// ---- MFMA shim ----
template <typename T, typename = void>
struct mfma_takes : std::false_type {};
template <typename T>
struct mfma_takes<T, std::void_t<decltype(__builtin_amdgcn_mfma_f32_16x16x32_bf16(
    std::declval<T>(), std::declval<T>(), std::declval<f32x4>(), 0, 0, 0))>> : std::true_type {};

template <typename AB>
static __device__ __forceinline__ f32x4 mfma_any(AB a, AB b, f32x4 c) {
  return __builtin_amdgcn_mfma_f32_16x16x32_bf16(a, b, c, 0, 0, 0);
}

template <typename S8 = s16x8, typename B8 = b16x8>
static __device__ __forceinline__ f32x4 MFMA_BF16(s16x8 a, s16x8 b, f32x4 c) {
  if constexpr (mfma_takes<S8>::value)
    return mfma_any<S8>(__builtin_bit_cast(S8, a), __builtin_bit_cast(S8, b), c);
  else
    return mfma_any<B8>(__builtin_bit_cast(B8, a), __builtin_bit_cast(B8, b), c);
}

static __device__ __forceinline__ void gld_lds16(const void* g, void* l) {
  __builtin_amdgcn_global_load_lds((const __attribute__((address_space(1))) void*)g,
                                   (__attribute__((address_space(3))) void*)l, 16, 0, 0);
}

// ---------------- fp32 -> bf16 conversion (x) ----------------
__global__ __launch_bounds__(256) void cvt_x_kernel(const float* __restrict__ in,
                                                    u16* __restrict__ out) {
  long i = ((long)blockIdx.x * 256 + threadIdx.x) * 8;
  float4 a = *(const float4*)(in + i);
  float4 b = *(const float4*)(in + i + 4);
  s16x8 o;
  o[0] = (short)f2b(a.x); o[1] = (short)f2b(a.y); o[2] = (short)f2b(a.z); o[3] = (short)f2b(a.w);
  o[4] = (short)f2b(b.x); o[5] = (short)f2b(b.y); o[6] = (short)f2b(b.z); o[7] = (short)f2b(b.w);
  *(s16x8*)(out + i) = o;
}

// ---------------- transpose + convert 4 x W, fused ----------------
__global__ __launch_bounds__(256) void transpose_cvt4_kernel(
    const float* __restrict__ W0, const float* __restrict__ W1,
    const float* __restrict__ W2, const float* __restrict__ W3,
    u16* __restrict__ D0, u16* __restrict__ D1, u16* __restrict__ D2, u16* __restrict__ D3) {
  __shared__ float tile[32][33];
  const float* W; u16* D;
  switch (blockIdx.z) {
    case 0:  W = W0; D = D0; break;
    case 1:  W = W1; D = D1; break;
    case 2:  W = W2; D = D2; break;
    default: W = W3; D = D3; break;
  }
  int n0 = blockIdx.x * 32, k0 = blockIdx.y * 32;
  int tx = threadIdx.x & 31, ty = threadIdx.x >> 5;
#pragma unroll
  for (int i = ty; i < 32; i += 8)
    tile[i][tx] = W[(long)(k0 + i) * EMB + n0 + tx];
  __syncthreads();
#pragma unroll
  for (int i = ty; i < 32; i += 8)
    D[(long)(n0 + i) * EMB + k0 + tx] = f2b(tile[tx][i]);
}

// ========== 256x256 GEMM, 8 waves, 64KB LDS (4 slots) -> 2 blocks/CU ==========
// NOTE launch_bounds: hipcc's 2nd arg behaves as min BLOCKS/CU (measured r12-r15:
// (512,2)->112 VGPR, (512,4)->64, (1024,4)->64, (1024,8)->32). (512,2) = 16 waves/CU
// = 4 waves/SIMD -> 128-VGPR cap; this body compiles at 112 (r3-r13). 64KB LDS x2 fits.
// Slots (u16): SA0=0 SA1=8192 SB0=16384 SB1=24576 (16KB each; A/B half-K-tiles).
// Tile t: P1 reads SA0(mh0)+SB0 | stage SA1<-A(t,+32);  P2 reads SA0(mh1) | stage SB0'<-B(t+1,+0)
//         P3 reads SA1(mh0)+SB1 | stage SA0'<-A(t+1,+0); P4 reads SA1(mh1)| stage SB1'<-B(t+1,+32)
// Waits: vmcnt(2) ONLY at P2-end and P4-end (2 loads/stage):
//   P2-end drains SB1,SA1 (read P3) keep SB0'; P4-end drains SB0',SA0' (read next-P1) keep SB1'.
// Leads: SB0',SB1' = 2-phase; SA1,SA0' = 1-phase (absorbed by co-resident 2nd block).
// Prologue: SA0,SB0,SB1 (6 loads); vm(2) drains SA0,SB0; bar.
#define SA0_ 0
#define SA1_ 8192
#define SB0_ 16384
#define SB1_ 24576

__global__ __launch_bounds__(512, 2) void gemm8p_kernel(
    const u16* __restrict__ A, const u16* __restrict__ Bt,
    const float* __restrict__ b0, const float* __restrict__ b1, const float* __restrict__ b2,
    void* __restrict__ Cp, u16* __restrict__ Qb, u16* __restrict__ Kp, u16* __restrict__ Vt,
    int N, int out_f32) {
  __shared__ __align__(16) u16 smem[32768];   // 64 KiB
  const int tid = threadIdx.x;
  const int w = tid >> 6, lane = tid & 63;
  const int wm = w >> 2, wn = w & 3;
  const int frow = lane & 15, fg = lane >> 4;

  const int nwg = gridDim.x;
  const int bid = ((int)blockIdx.x & 7) * (nwg >> 3) + ((int)blockIdx.x >> 3);
  const int nbn = N >> 8;
  const int bm = bid / nbn, bn = bid % nbn;

  int offA[8];
#pragma unroll
  for (int j = 0; j < 8; j++) {
    int row = wm * 128 + j * 16 + frow;
    offA[j] = row * 32 + ((fg ^ ((row ^ (row >> 2)) & 3)) << 3);
  }
  int offB[4];
#pragma unroll
  for (int j = 0; j < 4; j++) {
    int row = wn * 64 + j * 16 + frow;
    offB[j] = row * 32 + ((fg ^ ((row ^ (row >> 2)) & 3)) << 3);
  }
  int srow[2], soff[2];
#pragma unroll
  for (int L = 0; L < 2; L++) {
    int lin = L * 512 + tid;
    int r = lin >> 2;
    srow[L] = r;
    soff[L] = (((lin & 3) ^ ((r ^ (r >> 2)) & 3)) << 3);
  }
  const u16* Abase = A + (long)bm * 256 * KDIM;
  const u16* Bbase = Bt + (long)bn * 256 * KDIM;

  f32x4 acc[8][4];
#pragma unroll
  for (int m = 0; m < 8; m++)
#pragma unroll
    for (int n = 0; n < 4; n++) acc[m][n] = (f32x4)0.0f;

  auto STAGE = [&](const u16* gb, int kcol, int slot) {
#pragma unroll
    for (int L = 0; L < 2; L++)
      gld_lds16(gb + (long)srow[L] * KDIM + kcol + soff[L],
                &smem[slot + (L * 512 + w * 64) * 8]);
  };

  s16x8 af[4], bf[4];

  STAGE(Abase, 0, SA0_); STAGE(Bbase, 0, SB0_); STAGE(Bbase, 32, SB1_);
  asm volatile("s_waitcnt vmcnt(2)" ::: "memory");
  asm volatile("s_barrier" ::: "memory");

#define PHASE(ASL, BSL, mh, RDB, GB, KCOL, SLOT, DOVM)                        \
  {                                                                           \
    if (RDB) {                                                                \
      _Pragma("unroll") for (int n = 0; n < 4; n++)                           \
        bf[n] = *(const s16x8*)&smem[BSL + offB[n]];                          \
    }                                                                         \
    _Pragma("unroll") for (int m = 0; m < 4; m++)                             \
      af[m] = *(const s16x8*)&smem[ASL + offA[(mh) * 4 + m]];                 \
    STAGE(GB, KCOL, SLOT);                                                    \
    asm volatile("s_barrier" ::: "memory");                                   \
    __builtin_amdgcn_s_setprio(1);                                            \
    _Pragma("unroll") for (int m = 0; m < 4; m++)                             \
      _Pragma("unroll") for (int n = 0; n < 4; n++)                           \
        acc[(mh) * 4 + m][n] = MFMA_BF16(af[m], bf[n], acc[(mh) * 4 + m][n]); \
    __builtin_amdgcn_s_setprio(0);                                            \
    if (DOVM) asm volatile("s_waitcnt vmcnt(2)" ::: "memory");                \
    asm volatile("s_barrier" ::: "memory");                                   \
  }

#pragma unroll 1
  for (int t = 0; t < 16; t++) {
    const int cur = t * 64;
    const int nxt = ((t + 1) & 15) * 64;   // wraps harmlessly on last iter (data unused)
    PHASE(SA0_, SB0_, 0, 1, Abase, cur + 32, SA1_, 0)
    PHASE(SA0_, SB0_, 1, 0, Bbase, nxt,      SB0_, 1)
    PHASE(SA1_, SB1_, 0, 1, Abase, nxt,      SA0_, 0)
    PHASE(SA1_, SB1_, 1, 0, Bbase, nxt + 32, SB1_, 1)
  }
#undef PHASE

  asm volatile("s_waitcnt vmcnt(0) lgkmcnt(0)" ::: "memory");
  asm volatile("s_barrier" ::: "memory");

  const int Mbase = bm * 256 + wm * 128;

  if (!out_f32) {
    const int g = bn * 256 + wn * 64;      // wave's global col slab = one head
    const int part = g >> 10;              // 0=Q 1=K 2=V
    const int head = (g & 1023) >> 6;
    const float* bias = (part == 0) ? b0 : ((part == 1) ? b1 : b2);
    const float qs = (part == 0) ? QSCALE : 1.0f;   // fold score scale into Q
    float bv[4];
#pragma unroll
    for (int n = 0; n < 4; n++) bv[n] = bias[(g & 1023) + n * 16 + frow];

    if (part == 2) {
      // ---- V: per-wave [64][40]-u16 transpose bounce -> full-sector coalesced stores.
      u16* vbuf = &smem[w * 2560];         // 5 KB/wave x8 = 40 KB <= 64 KB
      const int batch = Mbase >> 12;
      u16* dstb = Vt + ((long)(batch * 16 + head)) * BHSTRIDE;
#pragma unroll
      for (int mf2 = 0; mf2 < 4; mf2++) {
        const int s0 = (Mbase & 4095) + mf2 * 32;
#pragma unroll
        for (int half = 0; half < 2; half++) {
          const int mf = mf2 * 2 + half;
#pragma unroll
          for (int n = 0; n < 4; n++) {
            const int d = n * 16 + frow;
#pragma unroll
            for (int r = 0; r < 4; r++)
              vbuf[d * 40 + half * 16 + 4 * fg + r] = f2b(acc[mf][n][r] + bv[n]);
          }
        }
        asm volatile("s_waitcnt lgkmcnt(0)" ::: "memory");
        __builtin_amdgcn_sched_barrier(0);
#pragma unroll
        for (int i = 0; i < 4; i++) {
          const int d = i * 16 + (lane >> 2);
          const int sl = lane & 3;
          s16x8 v = *(const s16x8*)&vbuf[d * 40 + sl * 8];
          *(s16x8*)(dstb + (long)d * S_LEN + s0 + sl * 8) = v;
        }
        asm volatile("s_waitcnt lgkmcnt(0)" ::: "memory");
        __builtin_amdgcn_sched_barrier(0);
      }
    } else {
      // ---- Q/K: swizzled wave-private bounce -> coalesced b128 stores
      u16* buf = &smem[w * 2048];            // 4 KB/wave x8 = 32 KB
#pragma unroll
      for (int mf2 = 0; mf2 < 4; mf2++) {
#pragma unroll
        for (int half = 0; half < 2; half++) {
          const int mf = mf2 * 2 + half;
#pragma unroll
          for (int n = 0; n < 4; n++)
#pragma unroll
            for (int r = 0; r < 4; r++) {
              int row32 = half * 16 + 4 * fg + r;
              int col = n * 16 + frow;
              buf[row32 * 64 + (((col >> 3) ^ (row32 & 7)) << 3) + (col & 7)] =
                  f2b((acc[mf][n][r] + bv[n]) * qs);
            }
        }
        asm volatile("s_waitcnt lgkmcnt(0)" ::: "memory");
        __builtin_amdgcn_sched_barrier(0);
        const int s0 = Mbase + mf2 * 32;
#pragma unroll
        for (int i = 0; i < 4; i++) {
          int flat = lane + 64 * i;
          int row32 = flat >> 3, ch = flat & 7;
          s16x8 v = *(const s16x8*)&buf[row32 * 64 + ((ch ^ (row32 & 7)) << 3)];
          int s = s0 + row32;
          u16* dst = (part == 0)
              ? (Qb + (long)s * 1024 + head * 64 + ch * 8)
              : (Kp + ((long)(s >> 12) * 16 + head) * BHSTRIDE + (long)(s & 4095) * 64 + ch * 8);
          *(s16x8*)dst = v;
        }
        asm volatile("s_waitcnt lgkmcnt(0)" ::: "memory");
        __builtin_amdgcn_sched_barrier(0);
      }
    }
  } else {
    // ---- f32 writer (gemm2): swizzled pitch-64 f32 bounce ----
    float* fbuf = (float*)&smem[w * 2048];   // [16][64] f32, 4 KB/wave x8 = 32 KB
    const long crow0 = (long)Mbase * N + bn * 256 + wn * 64;
#pragma unroll
    for (int mf = 0; mf < 8; mf++) {
#pragma unroll
      for (int n = 0; n < 4; n++) {
        float bvv = b0[(bn * 256 + wn * 64 + n * 16 + frow) & 1023];
#pragma unroll
        for (int r = 0; r < 4; r++) {
          int row = 4 * fg + r;
          int o = 4 * n + (frow >> 2);
          fbuf[row * 64 + ((o ^ (row & 7)) << 2) + (frow & 3)] = acc[mf][n][r] + bvv;
        }
      }
      asm volatile("s_waitcnt lgkmcnt(0)" ::: "memory");
      __builtin_amdgcn_sched_barrier(0);
#pragma unroll
      for (int i = 0; i < 4; i++) {
        int flat = lane + 64 * i;
        int row = flat >> 4, oct = lane & 15;
        float4 v = *(const float4*)&fbuf[row * 64 + ((oct ^ (row & 7)) << 2)];
        *(float4*)((float*)Cp + crow0 + (long)(mf * 16 + row) * N + oct * 4) = v;
      }
      asm volatile("s_waitcnt lgkmcnt(0)" ::: "memory");
      __builtin_amdgcn_sched_barrier(0);
    }
  }
}

// ---------------- local attention (unchanged from r13) ----------------
#define QBLK 128

__global__ __launch_bounds__(256) void attn_kernel(const u16* __restrict__ Qb,
                                                   const u16* __restrict__ Kp,
                                                   const u16* __restrict__ Vt,
                                                   u16* __restrict__ Oa) {
  __shared__ __align__(16) u16 smem[16384];   // lK[2][64][64] + lV[2][64][64] = 32KB

  const int tid = threadIdx.x;
  const int w = tid >> 6, lane = tid & 63;
  const int frow = lane & 15, fg = lane >> 4;

  const int nq = S_LEN / QBLK;             // 32
  int bid = (int)blockIdx.x;
  bid = (bid & 7) * ((NB * NH * nq) >> 3) + (bid >> 3);   // XCD swizzle
  const int b = bid / (NH * nq);
  const int rem = bid % (NH * nq);
  const int h = rem / nq;
  const int qt = rem % nq;
  const int q0 = qt * QBLK;
  const int qw0 = q0 + 32 * w;

  const u16* Kpb = Kp + (long)(b * NH + h) * BHSTRIDE;
  const u16* Vtb = Vt + (long)(b * NH + h) * BHSTRIDE;

  s16x8 qf[2][2];
#pragma unroll
  for (int m = 0; m < 2; m++)
#pragma unroll
    for (int kk = 0; kk < 2; kk++)
      qf[m][kk] = *(const s16x8*)(Qb + (long)(b * S_LEN + qw0 + 16 * m + frow) * 1024 +
                                  h * 64 + kk * 32 + 8 * fg);

  f32x4 acc[2][4];
#pragma unroll
  for (int m = 0; m < 2; m++)
#pragma unroll
    for (int n = 0; n < 4; n++) acc[m][n] = (f32x4)0.0f;
  float mrow[2] = {-1e30f, -1e30f};
  float lrow[2] = {0.f, 0.f};

  const int r8 = lane >> 3;
  const int cs = ((lane & 7) ^ r8) << 3;     // swizzled source chunk (u16 units)

  auto STAGE = [&](int kvb, int bufi) {
#pragma unroll
    for (int pass = 0; pass < 2; pass++) {
      int rbase = pass * 32 + w * 8;
      gld_lds16(Kpb + (long)(kvb + rbase + r8) * 64 + cs, &smem[bufi * 4096 + rbase * 64]);
      gld_lds16(Vtb + (long)(rbase + r8) * S_LEN + kvb + cs, &smem[8192 + bufi * 4096 + rbase * 64]);
    }
  };

  const int tlo = (q0 == 0) ? 2 : 0;
  const int thi = (q0 == S_LEN - QBLK) ? 3 : 5;

  STAGE(q0 - 128 + 64 * tlo, 0);

#pragma unroll 1
  for (int t = tlo; t <= thi; t++) {
    const int cur = (t - tlo) & 1;
    const int kvb = q0 - 128 + 64 * t;
    if (t < thi) {
      STAGE(kvb + 64, cur ^ 1);
      asm volatile("s_waitcnt vmcnt(4)" ::: "memory");
    } else {
      asm volatile("s_waitcnt vmcnt(0)" ::: "memory");
    }
    asm volatile("s_barrier" ::: "memory");

    const bool active = (kvb + 63 >= qw0 - 128) && (kvb <= qw0 + 159);
    if (active) {
      const u16* lK = &smem[cur * 4096];
      const u16* lV = &smem[8192 + cur * 4096];
      const int delta = kvb - qw0;
      const bool interior = (delta >= -97) && (delta <= 65);
      f32x4 sfr[2][4];
#pragma unroll
      for (int m = 0; m < 2; m++)
#pragma unroll
        for (int n = 0; n < 4; n++) sfr[m][n] = (f32x4)0.0f;
#pragma unroll
      for (int kk = 0; kk < 2; kk++) {
        s16x8 kb[4];
#pragma unroll
        for (int n = 0; n < 4; n++)
          kb[n] = *(const s16x8*)&lK[(16 * n + frow) * 64 + (((fg + 4 * kk) ^ (frow & 7)) << 3)];
#pragma unroll
        for (int m = 0; m < 2; m++)
#pragma unroll
          for (int n = 0; n < 4; n++)
            sfr[m][n] = MFMA_BF16(kb[n], qf[m][kk], sfr[m][n]);
      }
      // ---- softmax in log2 domain ----
#pragma unroll
      for (int m = 0; m < 2; m++) {
        float tmax = -1e30f;
        if (interior) {
#pragma unroll
          for (int n = 0; n < 4; n++)
#pragma unroll
            for (int r = 0; r < 4; r++) tmax = fmaxf(tmax, sfr[m][n][r]);
        } else {
          const int dbase = kvb - (qw0 + 16 * m + frow) + 128 + 4 * fg;  // + 16n + r
#pragma unroll
          for (int n = 0; n < 4; n++)
#pragma unroll
            for (int r = 0; r < 4; r++) {
              bool valid = (unsigned)(dbase + 16 * n + r) <= 256u;
              float xv = valid ? sfr[m][n][r] : -1e30f;
              sfr[m][n][r] = xv;
              tmax = fmaxf(tmax, xv);
            }
        }
        tmax = fmaxf(tmax, __shfl_xor(tmax, 16));
        tmax = fmaxf(tmax, __shfl_xor(tmax, 32));
        if (!__all(tmax - mrow[m] <= THR2)) {
          float mnew = fmaxf(mrow[m], tmax);
          float al = exp2_fast(mrow[m] - mnew);
          mrow[m] = mnew;
          lrow[m] *= al;
          float a4[4];
#pragma unroll
          for (int r = 0; r < 4; r++) a4[r] = __shfl(al, 20 * fg + r);
#pragma unroll
          for (int nd = 0; nd < 4; nd++)
#pragma unroll
            for (int r = 0; r < 4; r++) acc[m][nd][r] *= a4[r];
        }
        float ps = 0.f;
#pragma unroll
        for (int n = 0; n < 4; n++)
#pragma unroll
          for (int r = 0; r < 4; r++) {
            float e = exp2_fast(sfr[m][n][r] - mrow[m]);   // masked: exp2(-huge) -> 0
            sfr[m][n][r] = e;
            ps += e;
          }
        ps += __shfl_xor(ps, 16);
        ps += __shfl_xor(ps, 32);
        lrow[m] += ps;
      }
      s16x8 pa[2][2];
#pragma unroll
      for (int m = 0; m < 2; m++)
#pragma unroll
        for (int kt = 0; kt < 2; kt++)
#pragma unroll
          for (int j = 0; j < 8; j++)
            pa[m][kt][j] = (short)f2b(sfr[m][2 * kt + (j >> 2)][j & 3]);
#pragma unroll
      for (int kt = 0; kt < 2; kt++)
#pragma unroll
        for (int nd = 0; nd < 4; nd++) {
          const int d = 16 * nd + frow;
          const int key = frow & 7;
          const int olo = (4 * kt + (fg >> 1)) ^ key;
          const int ohi = (4 * kt + 2 + (fg >> 1)) ^ key;
          s16x4 lo = *(const s16x4*)&lV[d * 64 + olo * 8 + (fg & 1) * 4];
          s16x4 hi = *(const s16x4*)&lV[d * 64 + ohi * 8 + (fg & 1) * 4];
          s16x8 vb;
          vb[0] = lo[0]; vb[1] = lo[1]; vb[2] = lo[2]; vb[3] = lo[3];
          vb[4] = hi[0]; vb[5] = hi[1]; vb[6] = hi[2]; vb[7] = hi[3];
#pragma unroll
          for (int m = 0; m < 2; m++)
            acc[m][nd] = MFMA_BF16(pa[m][kt], vb, acc[m][nd]);
        }
    }
    asm volatile("s_barrier" ::: "memory");
  }

  float i4[2][4];
#pragma unroll
  for (int m = 0; m < 2; m++) {
    float inv = 1.0f / lrow[m];
#pragma unroll
    for (int r = 0; r < 4; r++) i4[m][r] = __shfl(inv, 20 * fg + r);
  }
  u16* bb = &smem[w * 2048];   // [32][64] swizzled
#pragma unroll
  for (int m = 0; m < 2; m++)
#pragma unroll
    for (int nd = 0; nd < 4; nd++)
#pragma unroll
      for (int r = 0; r < 4; r++) {
        int row32 = 16 * m + 4 * fg + r;
        int col = 16 * nd + frow;
        bb[row32 * 64 + (((col >> 3) ^ (row32 & 7)) << 3) + (col & 7)] =
            f2b(acc[m][nd][r] * i4[m][r]);
      }
  asm volatile("s_waitcnt lgkmcnt(0)" ::: "memory");
  __builtin_amdgcn_sched_barrier(0);
  u16* Ob = Oa + ((long)(b * S_LEN + qw0)) * EMB + h * HD;
#pragma unroll
  for (int i = 0; i < 4; i++) {
    int flat = lane + 64 * i;
    int row32 = flat >> 3, ch = flat & 7;
    s16x8 v = *(const s16x8*)&bb[row32 * 64 + ((ch ^ (row32 & 7)) << 3)];
    *(s16x8*)(Ob + (long)row32 * EMB + ch * 8) = v;
  }
}

extern "C" void kernel_launch(void* const* d_in, const int* in_sizes, int n_in,
                              void* d_out, int out_size, void* d_ws, size_t ws_size,
                              hipStream_t stream) {
  const float* x  = (const float*)d_in[0];
  const float* Wq = (const float*)d_in[1];
  const float* bq = (const float*)d_in[2];
  const float* Wk = (const float*)d_in[3];
  const float* bk = (const float*)d_in[4];
  const float* Wv = (const float*)d_in[5];
  const float* bv = (const float*)d_in[6];
  const float* Wo = (const float*)d_in[7];
  const float* bo = (const float*)d_in[8];

  char* ws = (char*)d_ws;
  u16* xb   = (u16*)ws;  ws += (size_t)NROWS * EMB * 2;        // 32 MB
  u16* Wt   = (u16*)ws;  ws += (size_t)3 * EMB * EMB * 2;      // 6 MB
  u16* Wot  = (u16*)ws;  ws += (size_t)EMB * EMB * 2;          // 2 MB
  u16* Qbuf = (u16*)ws;  ws += (size_t)NROWS * EMB * 2;        // 32 MB
  u16* Kpb  = (u16*)ws;  ws += (size_t)NB * NH * BHSTRIDE * 2; // 32 MB
  u16* Vtb  = (u16*)ws;  ws += (size_t)NB * NH * BHSTRIDE * 2; // 32 MB
  u16* Oab  = (u16*)ws;  ws += (size_t)NROWS * EMB * 2;        // 32 MB

  cvt_x_kernel<<<(NROWS * EMB) / (256 * 8), 256, 0, stream>>>(x, xb);

  dim3 tg(EMB / 32, EMB / 32, 4);
  transpose_cvt4_kernel<<<tg, 256, 0, stream>>>(
      Wq, Wk, Wv, Wo, Wt, Wt + (size_t)EMB * EMB, Wt + (size_t)2 * EMB * EMB, Wot);

  gemm8p_kernel<<<(NROWS / 256) * (3 * EMB / 256), 512, 0, stream>>>(
      xb, Wt, bq, bk, bv, nullptr, Qbuf, Kpb, Vtb, 3 * EMB, 0);

  attn_kernel<<<NB * NH * (S_LEN / QBLK), 256, 0, stream>>>(Qbuf, Kpb, Vtb, Oab);

  gemm8p_kernel<<<(NROWS / 256) * (EMB / 256), 512, 0, stream>>>(
      Oab, Wot, bo, bo, bo, d_out, nullptr, nullptr, nullptr, EMB, 1);
}

// Round 18
// 237.571 us; speedup vs baseline: 9.3198x; 1.0018x over previous
//
#include <hip/hip_runtime.h>
#include <hip/hip_bf16.h>
#include <type_traits>
#include <math.h>

typedef unsigned short u16;
typedef __attribute__((ext_vector_type(8))) short  s16x8;
typedef __attribute__((ext_vector_type(4))) short  s16x4;
typedef __attribute__((ext_vector_type(8))) __bf16 b16x8;
typedef __attribute__((ext_vector_type(4))) float  f32x4;

#define S_LEN 4096
#define NB    4
#define EMB   1024
#define NH    16
#define HD    64
#define NROWS (NB * S_LEN)   // 16384
#define KDIM  1024
#define BHSTRIDE (S_LEN * HD)   // 262144 u16 per (b,h) for Kp / Vt
#define QSCALE 0.18033688f      // 0.125 * log2(e): scores land in log2-domain
#define THR2   11.5429f         // defer-max threshold, 8 nats in log2 units

static __device__ __forceinline__ u16 f2b(float f) {
  __hip_bfloat16 h = __float2bfloat16(f);
  return __builtin_bit_cast(u16, h);
}

static __device__ __forceinline__ float exp2_fast(float x) {
#if __has_builtin(__builtin_amdgcn_exp2f)
  return __builtin_amdgcn_exp2f(x);   // raw v_exp_f32
#else
  return exp2f(x);
#endif
}

// ---- MFMA shim ----
template <typename T, typename = void>
struct mfma_takes : std::false_type {};
template <typename T>
struct mfma_takes<T, std::void_t<decltype(__builtin_amdgcn_mfma_f32_16x16x32_bf16(
    std::declval<T>(), std::declval<T>(), std::declval<f32x4>(), 0, 0, 0))>> : std::true_type {};

template <typename AB>
static __device__ __forceinline__ f32x4 mfma_any(AB a, AB b, f32x4 c) {
  return __builtin_amdgcn_mfma_f32_16x16x32_bf16(a, b, c, 0, 0, 0);
}

template <typename S8 = s16x8, typename B8 = b16x8>
static __device__ __forceinline__ f32x4 MFMA_BF16(s16x8 a, s16x8 b, f32x4 c) {
  if constexpr (mfma_takes<S8>::value)
    return mfma_any<S8>(__builtin_bit_cast(S8, a), __builtin_bit_cast(S8, b), c);
  else
    return mfma_any<B8>(__builtin_bit_cast(B8, a), __builtin_bit_cast(B8, b), c);
}

static __device__ __forceinline__ void gld_lds16(const void* g, void* l) {
  __builtin_amdgcn_global_load_lds((const __attribute__((address_space(1))) void*)g,
                                   (__attribute__((address_space(3))) void*)l, 16, 0, 0);
}

// ---------------- fp32 -> bf16 conversion (x) ----------------
__global__ __launch_bounds__(256) void cvt_x_kernel(const float* __restrict__ in,
                                                    u16* __restrict__ out) {
  long i = ((long)blockIdx.x * 256 + threadIdx.x) * 8;
  float4 a = *(const float4*)(in + i);
  float4 b = *(const float4*)(in + i + 4);
  s16x8 o;
  o[0] = (short)f2b(a.x); o[1] = (short)f2b(a.y); o[2] = (short)f2b(a.z); o[3] = (short)f2b(a.w);
  o[4] = (short)f2b(b.x); o[5] = (short)f2b(b.y); o[6] = (short)f2b(b.z); o[7] = (short)f2b(b.w);
  *(s16x8*)(out + i) = o;
}

// ---------------- transpose + convert 4 x W, fused ----------------
__global__ __launch_bounds__(256) void transpose_cvt4_kernel(
    const float* __restrict__ W0, const float* __restrict__ W1,
    const float* __restrict__ W2, const float* __restrict__ W3,
    u16* __restrict__ D0, u16* __restrict__ D1, u16* __restrict__ D2, u16* __restrict__ D3) {
  __shared__ float tile[32][33];
  const float* W; u16* D;
  switch (blockIdx.z) {
    case 0:  W = W0; D = D0; break;
    case 1:  W = W1; D = D1; break;
    case 2:  W = W2; D = D2; break;
    default: W = W3; D = D3; break;
  }
  int n0 = blockIdx.x * 32, k0 = blockIdx.y * 32;
  int tx = threadIdx.x & 31, ty = threadIdx.x >> 5;
#pragma unroll
  for (int i = ty; i < 32; i += 8)
    tile[i][tx] = W[(long)(k0 + i) * EMB + n0 + tx];
  __syncthreads();
#pragma unroll
  for (int i = ty; i < 32; i += 8)
    D[(long)(n0 + i) * EMB + k0 + tx] = f2b(tile[tx][i]);
}

// ========== 256x256 GEMM, 8 waves, 64KB LDS (4 slots) -> 2 blocks/CU ==========
// NOTE launch_bounds: hipcc's 2nd arg behaves as min BLOCKS/CU (measured r12-r15:
// (512,2)->112 VGPR, (512,4)->64, (1024,4)->64, (1024,8)->32). (512,2) = 16 waves/CU
// = 4 waves/SIMD -> 128-VGPR cap; this body compiles at ~100-112 VGPR. 64KB LDS x2 fits.
// Slots (u16): SA0=0 SA1=8192 SB0=16384 SB1=24576 (16KB each; A/B half-K-tiles).
// Tile t: P1 reads SA0(mh0)+SB0 | stage SA1<-A(t,+32);  P2 reads SA0(mh1) | stage SB0'<-B(t+1,+0)
//         P3 reads SA1(mh0)+SB1 | stage SA0'<-A(t+1,+0); P4 reads SA1(mh1)| stage SB1'<-B(t+1,+32)
// Waits: vmcnt(2) ONLY at P2-end and P4-end (2 loads/stage):
//   P2-end drains SB1,SA1 (read P3) keep SB0'; P4-end drains SB0',SA0' (read next-P1) keep SB1'.
// Leads: SB0',SB1' = 2-phase; SA1,SA0' = 1-phase (absorbed by co-resident 2nd block).
// Prologue: SA0,SB0,SB1 (6 loads); vm(2) drains SA0,SB0; bar.
#define SA0_ 0
#define SA1_ 8192
#define SB0_ 16384
#define SB1_ 24576

__global__ __launch_bounds__(512, 2) void gemm8p_kernel(
    const u16* __restrict__ A, const u16* __restrict__ Bt,
    const float* __restrict__ b0, const float* __restrict__ b1, const float* __restrict__ b2,
    void* __restrict__ Cp, u16* __restrict__ Qb, u16* __restrict__ Kp, u16* __restrict__ Vt,
    int N, int out_f32) {
  __shared__ __align__(16) u16 smem[32768];   // 64 KiB
  const int tid = threadIdx.x;
  const int w = tid >> 6, lane = tid & 63;
  const int wm = w >> 2, wn = w & 3;
  const int frow = lane & 15, fg = lane >> 4;

  const int nwg = gridDim.x;
  const int bid = ((int)blockIdx.x & 7) * (nwg >> 3) + ((int)blockIdx.x >> 3);
  const int nbn = N >> 8;
  const int bm = bid / nbn, bn = bid % nbn;

  int offA[8];
#pragma unroll
  for (int j = 0; j < 8; j++) {
    int row = wm * 128 + j * 16 + frow;
    offA[j] = row * 32 + ((fg ^ ((row ^ (row >> 2)) & 3)) << 3);
  }
  int offB[4];
#pragma unroll
  for (int j = 0; j < 4; j++) {
    int row = wn * 64 + j * 16 + frow;
    offB[j] = row * 32 + ((fg ^ ((row ^ (row >> 2)) & 3)) << 3);
  }
  int srow[2], soff[2];
#pragma unroll
  for (int L = 0; L < 2; L++) {
    int lin = L * 512 + tid;
    int r = lin >> 2;
    srow[L] = r;
    soff[L] = (((lin & 3) ^ ((r ^ (r >> 2)) & 3)) << 3);
  }
  const u16* Abase = A + (long)bm * 256 * KDIM;
  const u16* Bbase = Bt + (long)bn * 256 * KDIM;

  f32x4 acc[8][4];
#pragma unroll
  for (int m = 0; m < 8; m++)
#pragma unroll
    for (int n = 0; n < 4; n++) acc[m][n] = (f32x4)0.0f;

  auto STAGE = [&](const u16* gb, int kcol, int slot) {
#pragma unroll
    for (int L = 0; L < 2; L++)
      gld_lds16(gb + (long)srow[L] * KDIM + kcol + soff[L],
                &smem[slot + (L * 512 + w * 64) * 8]);
  };

  s16x8 af[4], bf[4];

  STAGE(Abase, 0, SA0_); STAGE(Bbase, 0, SB0_); STAGE(Bbase, 32, SB1_);
  asm volatile("s_waitcnt vmcnt(2)" ::: "memory");
  asm volatile("s_barrier" ::: "memory");

#define PHASE(ASL, BSL, mh, RDB, GB, KCOL, SLOT, DOVM)                        \
  {                                                                           \
    if (RDB) {                                                                \
      _Pragma("unroll") for (int n = 0; n < 4; n++)                           \
        bf[n] = *(const s16x8*)&smem[BSL + offB[n]];                          \
    }                                                                         \
    _Pragma("unroll") for (int m = 0; m < 4; m++)                             \
      af[m] = *(const s16x8*)&smem[ASL + offA[(mh) * 4 + m]];                 \
    STAGE(GB, KCOL, SLOT);                                                    \
    asm volatile("s_barrier" ::: "memory");                                   \
    __builtin_amdgcn_s_setprio(1);                                            \
    _Pragma("unroll") for (int m = 0; m < 4; m++)                             \
      _Pragma("unroll") for (int n = 0; n < 4; n++)                           \
        acc[(mh) * 4 + m][n] = MFMA_BF16(af[m], bf[n], acc[(mh) * 4 + m][n]); \
    __builtin_amdgcn_s_setprio(0);                                            \
    if (DOVM) asm volatile("s_waitcnt vmcnt(2)" ::: "memory");                \
    asm volatile("s_barrier" ::: "memory");                                   \
  }

#pragma unroll 1
  for (int t = 0; t < 16; t++) {
    const int cur = t * 64;
    const int nxt = ((t + 1) & 15) * 64;   // wraps harmlessly on last iter (data unused)
    PHASE(SA0_, SB0_, 0, 1, Abase, cur + 32, SA1_, 0)
    PHASE(SA0_, SB0_, 1, 0, Bbase, nxt,      SB0_, 1)
    PHASE(SA1_, SB1_, 0, 1, Abase, nxt,      SA0_, 0)
    PHASE(SA1_, SB1_, 1, 0, Bbase, nxt + 32, SB1_, 1)
  }
#undef PHASE

  asm volatile("s_waitcnt vmcnt(0) lgkmcnt(0)" ::: "memory");
  asm volatile("s_barrier" ::: "memory");

  const int Mbase = bm * 256 + wm * 128;

  if (!out_f32) {
    const int g = bn * 256 + wn * 64;      // wave's global col slab = one head
    const int part = g >> 10;              // 0=Q 1=K 2=V
    const int head = (g & 1023) >> 6;
    const float* bias = (part == 0) ? b0 : ((part == 1) ? b1 : b2);
    const float qs = (part == 0) ? QSCALE : 1.0f;   // fold score scale into Q
    float bv[4];
#pragma unroll
    for (int n = 0; n < 4; n++) bv[n] = bias[(g & 1023) + n * 16 + frow];

    if (part == 2) {
      // ---- V: per-wave [64][40]-u16 transpose bounce -> full-sector coalesced stores.
      u16* vbuf = &smem[w * 2560];         // 5 KB/wave x8 = 40 KB <= 64 KB
      const int batch = Mbase >> 12;
      u16* dstb = Vt + ((long)(batch * 16 + head)) * BHSTRIDE;
#pragma unroll
      for (int mf2 = 0; mf2 < 4; mf2++) {
        const int s0 = (Mbase & 4095) + mf2 * 32;
#pragma unroll
        for (int half = 0; half < 2; half++) {
          const int mf = mf2 * 2 + half;
#pragma unroll
          for (int n = 0; n < 4; n++) {
            const int d = n * 16 + frow;
#pragma unroll
            for (int r = 0; r < 4; r++)
              vbuf[d * 40 + half * 16 + 4 * fg + r] = f2b(acc[mf][n][r] + bv[n]);
          }
        }
        asm volatile("s_waitcnt lgkmcnt(0)" ::: "memory");
        __builtin_amdgcn_sched_barrier(0);
#pragma unroll
        for (int i = 0; i < 4; i++) {
          const int d = i * 16 + (lane >> 2);
          const int sl = lane & 3;
          s16x8 v = *(const s16x8*)&vbuf[d * 40 + sl * 8];
          *(s16x8*)(dstb + (long)d * S_LEN + s0 + sl * 8) = v;
        }
        asm volatile("s_waitcnt lgkmcnt(0)" ::: "memory");
        __builtin_amdgcn_sched_barrier(0);
      }
    } else {
      // ---- Q/K: swizzled wave-private bounce -> coalesced b128 stores
      u16* buf = &smem[w * 2048];            // 4 KB/wave x8 = 32 KB
#pragma unroll
      for (int mf2 = 0; mf2 < 4; mf2++) {
#pragma unroll
        for (int half = 0; half < 2; half++) {
          const int mf = mf2 * 2 + half;
#pragma unroll
          for (int n = 0; n < 4; n++)
#pragma unroll
            for (int r = 0; r < 4; r++) {
              int row32 = half * 16 + 4 * fg + r;
              int col = n * 16 + frow;
              buf[row32 * 64 + (((col >> 3) ^ (row32 & 7)) << 3) + (col & 7)] =
                  f2b((acc[mf][n][r] + bv[n]) * qs);
            }
        }
        asm volatile("s_waitcnt lgkmcnt(0)" ::: "memory");
        __builtin_amdgcn_sched_barrier(0);
        const int s0 = Mbase + mf2 * 32;
#pragma unroll
        for (int i = 0; i < 4; i++) {
          int flat = lane + 64 * i;
          int row32 = flat >> 3, ch = flat & 7;
          s16x8 v = *(const s16x8*)&buf[row32 * 64 + ((ch ^ (row32 & 7)) << 3)];
          int s = s0 + row32;
          u16* dst = (part == 0)
              ? (Qb + (long)s * 1024 + head * 64 + ch * 8)
              : (Kp + ((long)(s >> 12) * 16 + head) * BHSTRIDE + (long)(s & 4095) * 64 + ch * 8);
          *(s16x8*)dst = v;
        }
        asm volatile("s_waitcnt lgkmcnt(0)" ::: "memory");
        __builtin_amdgcn_sched_barrier(0);
      }
    }
  } else {
    // ---- f32 writer (gemm2): swizzled pitch-64 f32 bounce ----
    float* fbuf = (float*)&smem[w * 2048];   // [16][64] f32, 4 KB/wave x8 = 32 KB
    const long crow0 = (long)Mbase * N + bn * 256 + wn * 64;
#pragma unroll
    for (int mf = 0; mf < 8; mf++) {
#pragma unroll
      for (int n = 0; n < 4; n++) {
        float bvv = b0[(bn * 256 + wn * 64 + n * 16 + frow) & 1023];
#pragma unroll
        for (int r = 0; r < 4; r++) {
          int row = 4 * fg + r;
          int o = 4 * n + (frow >> 2);
          fbuf[row * 64 + ((o ^ (row & 7)) << 2) + (frow & 3)] = acc[mf][n][r] + bvv;
        }
      }
      asm volatile("s_waitcnt lgkmcnt(0)" ::: "memory");
      __builtin_amdgcn_sched_barrier(0);
#pragma unroll
      for (int i = 0; i < 4; i++) {
        int flat = lane + 64 * i;
        int row = flat >> 4, oct = lane & 15;
        float4 v = *(const float4*)&fbuf[row * 64 + ((oct ^ (row & 7)) << 2)];
        *(float4*)((float*)Cp + crow0 + (long)(mf * 16 + row) * N + oct * 4) = v;
      }
      asm volatile("s_waitcnt lgkmcnt(0)" ::: "memory");
      __builtin_amdgcn_sched_barrier(0);
    }
  }
}

// ---------------- local attention (log2-domain softmax; scale pre-folded into Q) ----------------
#define QBLK 128

__global__ __launch_bounds__(256) void attn_kernel(const u16* __restrict__ Qb,
                                                   const u16* __restrict__ Kp,
                                                   const u16* __restrict__ Vt,
                                                   u16* __restrict__ Oa) {
  __shared__ __align__(16) u16 smem[16384];   // lK[2][64][64] + lV[2][64][64] = 32KB

  const int tid = threadIdx.x;
  const int w = tid >> 6, lane = tid & 63;
  const int frow = lane & 15, fg = lane >> 4;

  const int nq = S_LEN / QBLK;             // 32
  int bid = (int)blockIdx.x;
  bid = (bid & 7) * ((NB * NH * nq) >> 3) + (bid >> 3);   // XCD swizzle
  const int b = bid / (NH * nq);
  const int rem = bid % (NH * nq);
  const int h = rem / nq;
  const int qt = rem % nq;
  const int q0 = qt * QBLK;
  const int qw0 = q0 + 32 * w;

  const u16* Kpb = Kp + (long)(b * NH + h) * BHSTRIDE;
  const u16* Vtb = Vt + (long)(b * NH + h) * BHSTRIDE;

  s16x8 qf[2][2];
#pragma unroll
  for (int m = 0; m < 2; m++)
#pragma unroll
    for (int kk = 0; kk < 2; kk++)
      qf[m][kk] = *(const s16x8*)(Qb + (long)(b * S_LEN + qw0 + 16 * m + frow) * 1024 +
                                  h * 64 + kk * 32 + 8 * fg);

  f32x4 acc[2][4];
#pragma unroll
  for (int m = 0; m < 2; m++)
#pragma unroll
    for (int n = 0; n < 4; n++) acc[m][n] = (f32x4)0.0f;
  float mrow[2] = {-1e30f, -1e30f};
  float lrow[2] = {0.f, 0.f};

  const int r8 = lane >> 3;
  const int cs = ((lane & 7) ^ r8) << 3;     // swizzled source chunk (u16 units)

  auto STAGE = [&](int kvb, int bufi) {
#pragma unroll
    for (int pass = 0; pass < 2; pass++) {
      int rbase = pass * 32 + w * 8;
      gld_lds16(Kpb + (long)(kvb + rbase + r8) * 64 + cs, &smem[bufi * 4096 + rbase * 64]);
      gld_lds16(Vtb + (long)(rbase + r8) * S_LEN + kvb + cs, &smem[8192 + bufi * 4096 + rbase * 64]);
    }
  };

  const int tlo = (q0 == 0) ? 2 : 0;
  const int thi = (q0 == S_LEN - QBLK) ? 3 : 5;

  STAGE(q0 - 128 + 64 * tlo, 0);

#pragma unroll 1
  for (int t = tlo; t <= thi; t++) {
    const int cur = (t - tlo) & 1;
    const int kvb = q0 - 128 + 64 * t;
    if (t < thi) {
      STAGE(kvb + 64, cur ^ 1);
      asm volatile("s_waitcnt vmcnt(4)" ::: "memory");
    } else {
      asm volatile("s_waitcnt vmcnt(0)" ::: "memory");
    }
    asm volatile("s_barrier" ::: "memory");

    const bool active = (kvb + 63 >= qw0 - 128) && (kvb <= qw0 + 159);
    if (active) {
      const u16* lK = &smem[cur * 4096];
      const u16* lV = &smem[8192 + cur * 4096];
      const int delta = kvb - qw0;
      const bool interior = (delta >= -97) && (delta <= 65);
      f32x4 sfr[2][4];
#pragma unroll
      for (int m = 0; m < 2; m++)
#pragma unroll
        for (int n = 0; n < 4; n++) sfr[m][n] = (f32x4)0.0f;
#pragma unroll
      for (int kk = 0; kk < 2; kk++) {
        s16x8 kb[4];
#pragma unroll
        for (int n = 0; n < 4; n++)
          kb[n] = *(const s16x8*)&lK[(16 * n + frow) * 64 + (((fg + 4 * kk) ^ (frow & 7)) << 3)];
#pragma unroll
        for (int m = 0; m < 2; m++)
#pragma unroll
          for (int n = 0; n < 4; n++)
            sfr[m][n] = MFMA_BF16(kb[n], qf[m][kk], sfr[m][n]);
      }
      // ---- softmax in log2 domain ----
#pragma unroll
      for (int m = 0; m < 2; m++) {
        float tmax = -1e30f;
        if (interior) {
#pragma unroll
          for (int n = 0; n < 4; n++)
#pragma unroll
            for (int r = 0; r < 4; r++) tmax = fmaxf(tmax, sfr[m][n][r]);
        } else {
          const int dbase = kvb - (qw0 + 16 * m + frow) + 128 + 4 * fg;  // + 16n + r
#pragma unroll
          for (int n = 0; n < 4; n++)
#pragma unroll
            for (int r = 0; r < 4; r++) {
              bool valid = (unsigned)(dbase + 16 * n + r) <= 256u;
              float xv = valid ? sfr[m][n][r] : -1e30f;
              sfr[m][n][r] = xv;
              tmax = fmaxf(tmax, xv);
            }
        }
        tmax = fmaxf(tmax, __shfl_xor(tmax, 16));
        tmax = fmaxf(tmax, __shfl_xor(tmax, 32));
        if (!__all(tmax - mrow[m] <= THR2)) {
          float mnew = fmaxf(mrow[m], tmax);
          float al = exp2_fast(mrow[m] - mnew);
          mrow[m] = mnew;
          lrow[m] *= al;
          float a4[4];
#pragma unroll
          for (int r = 0; r < 4; r++) a4[r] = __shfl(al, 20 * fg + r);
#pragma unroll
          for (int nd = 0; nd < 4; nd++)
#pragma unroll
            for (int r = 0; r < 4; r++) acc[m][nd][r] *= a4[r];
        }
        float ps = 0.f;
#pragma unroll
        for (int n = 0; n < 4; n++)
#pragma unroll
          for (int r = 0; r < 4; r++) {
            float e = exp2_fast(sfr[m][n][r] - mrow[m]);   // masked: exp2(-huge) -> 0
            sfr[m][n][r] = e;
            ps += e;
          }
        ps += __shfl_xor(ps, 16);
        ps += __shfl_xor(ps, 32);
        lrow[m] += ps;
      }
      s16x8 pa[2][2];
#pragma unroll
      for (int m = 0; m < 2; m++)
#pragma unroll
        for (int kt = 0; kt < 2; kt++)
#pragma unroll
          for (int j = 0; j < 8; j++)
            pa[m][kt][j] = (short)f2b(sfr[m][2 * kt + (j >> 2)][j & 3]);
#pragma unroll
      for (int kt = 0; kt < 2; kt++)
#pragma unroll
        for (int nd = 0; nd < 4; nd++) {
          const int d = 16 * nd + frow;
          const int key = frow & 7;
          const int olo = (4 * kt + (fg >> 1)) ^ key;
          const int ohi = (4 * kt + 2 + (fg >> 1)) ^ key;
          s16x4 lo = *(const s16x4*)&lV[d * 64 + olo * 8 + (fg & 1) * 4];
          s16x4 hi = *(const s16x4*)&lV[d * 64 + ohi * 8 + (fg & 1) * 4];
          s16x8 vb;
          vb[0] = lo[0]; vb[1] = lo[1]; vb[2] = lo[2]; vb[3] = lo[3];
          vb[4] = hi[0]; vb[5] = hi[1]; vb[6] = hi[2]; vb[7] = hi[3];
#pragma unroll
          for (int m = 0; m < 2; m++)
            acc[m][nd] = MFMA_BF16(pa[m][kt], vb, acc[m][nd]);
        }
    }
    asm volatile("s_barrier" ::: "memory");
  }

  float i4[2][4];
#pragma unroll
  for (int m = 0; m < 2; m++) {
    float inv = 1.0f / lrow[m];
#pragma unroll
    for (int r = 0; r < 4; r++) i4[m][r] = __shfl(inv, 20 * fg + r);
  }
  u16* bb = &smem[w * 2048];   // [32][64] swizzled
#pragma unroll
  for (int m = 0; m < 2; m++)
#pragma unroll
    for (int nd = 0; nd < 4; nd++)
#pragma unroll
      for (int r = 0; r < 4; r++) {
        int row32 = 16 * m + 4 * fg + r;
        int col = 16 * nd + frow;
        bb[row32 * 64 + (((col >> 3) ^ (row32 & 7)) << 3) + (col & 7)] =
            f2b(acc[m][nd][r] * i4[m][r]);
      }
  asm volatile("s_waitcnt lgkmcnt(0)" ::: "memory");
  __builtin_amdgcn_sched_barrier(0);
  u16* Ob = Oa + ((long)(b * S_LEN + qw0)) * EMB + h * HD;
#pragma unroll
  for (int i = 0; i < 4; i++) {
    int flat = lane + 64 * i;
    int row32 = flat >> 3, ch = flat & 7;
    s16x8 v = *(const s16x8*)&bb[row32 * 64 + ((ch ^ (row32 & 7)) << 3)];
    *(s16x8*)(Ob + (long)row32 * EMB + ch * 8) = v;
  }
}

extern "C" void kernel_launch(void* const* d_in, const int* in_sizes, int n_in,
                              void* d_out, int out_size, void* d_ws, size_t ws_size,
                              hipStream_t stream) {
  const float* x  = (const float*)d_in[0];
  const float* Wq = (const float*)d_in[1];
  const float* bq = (const float*)d_in[2];
  const float* Wk = (const float*)d_in[3];
  const float* bk = (const float*)d_in[4];
  const float* Wv = (const float*)d_in[5];
  const float* bv = (const float*)d_in[6];
  const float* Wo = (const float*)d_in[7];
  const float* bo = (const float*)d_in[8];

  char* ws = (char*)d_ws;
  u16* xb   = (u16*)ws;  ws += (size_t)NROWS * EMB * 2;        // 32 MB
  u16* Wt   = (u16*)ws;  ws += (size_t)3 * EMB * EMB * 2;      // 6 MB
  u16* Wot  = (u16*)ws;  ws += (size_t)EMB * EMB * 2;          // 2 MB
  u16* Qbuf = (u16*)ws;  ws += (size_t)NROWS * EMB * 2;        // 32 MB
  u16* Kpb  = (u16*)ws;  ws += (size_t)NB * NH * BHSTRIDE * 2; // 32 MB
  u16* Vtb  = (u16*)ws;  ws += (size_t)NB * NH * BHSTRIDE * 2; // 32 MB
  u16* Oab  = (u16*)ws;  ws += (size_t)NROWS * EMB * 2;        // 32 MB

  cvt_x_kernel<<<(NROWS * EMB) / (256 * 8), 256, 0, stream>>>(x, xb);

  dim3 tg(EMB / 32, EMB / 32, 4);
  transpose_cvt4_kernel<<<tg, 256, 0, stream>>>(
      Wq, Wk, Wv, Wo, Wt, Wt + (size_t)EMB * EMB, Wt + (size_t)2 * EMB * EMB, Wot);

  gemm8p_kernel<<<(NROWS / 256) * (3 * EMB / 256), 512, 0, stream>>>(
      xb, Wt, bq, bk, bv, nullptr, Qbuf, Kpb, Vtb, 3 * EMB, 0);

  attn_kernel<<<NB * NH * (S_LEN / QBLK), 256, 0, stream>>>(Qbuf, Kpb, Vtb, Oab);

  gemm8p_kernel<<<(NROWS / 256) * (EMB / 256), 512, 0, stream>>>(
      Oab, Wot, bo, bo, bo, d_out, nullptr, nullptr, nullptr, EMB, 1);
}